// Round 6
// baseline (1850.444 us; speedup 1.0000x reference)
//
#include <hip/hip_runtime.h>
#include <math.h>

using u16 = unsigned short;
using u32 = unsigned int;
typedef __attribute__((ext_vector_type(8))) short bf16x8;
typedef __attribute__((ext_vector_type(4))) float f32x4;

#define NPLANE 65536
#define BELEMS ((size_t)6291456) /* 96*65536 elements per batch */

__device__ __forceinline__ float bf2f(u16 u) { return __uint_as_float(((u32)u) << 16); }
__device__ __forceinline__ float lo2f(u32 v) { return __uint_as_float(v << 16); }
__device__ __forceinline__ float hi2f(u32 v) { return __uint_as_float(v & 0xffff0000u); }
__device__ __forceinline__ u16 f2bf(float f) {
  if (!__builtin_isfinite(f)) return (u16)0x5F80;  // diagnostic sentinel ~1.8e19
  u32 u = __float_as_uint(f);
  return (u16)((u + 0x7fffu + ((u >> 16) & 1u)) >> 16);
}
__device__ __forceinline__ float4 cvt4(ushort4 v) {
  return make_float4(bf2f(v.x), bf2f(v.y), bf2f(v.z), bf2f(v.w));
}
__device__ __forceinline__ ushort4 pack4(float a, float b, float c, float d) {
  ushort4 o; o.x = f2bf(a); o.y = f2bf(b); o.z = f2bf(c); o.w = f2bf(d); return o;
}

union U16x8 { uint4 u4; bf16x8 v; u16 s[8]; };

// ---------------- dtype detect: ln1_w[0] == 1.0. bf16 -> 0x3F80, fp32 low half -> 0x0000
__global__ void k_detect(const u16* __restrict__ p, u32* __restrict__ flag) {
  if (blockIdx.x == 0 && threadIdx.x == 0) *flag = (p[0] == (u16)0x3F80) ? 0u : 1u;
}

// ---------------- small param convert -> f32
__global__ __launch_bounds__(256) void k_cvt_f32(const void* __restrict__ src,
                                                 float* __restrict__ dst, int n,
                                                 const u32* __restrict__ fl) {
  const int i = blockIdx.x * 256 + threadIdx.x;
  if (i >= n) return;
  dst[i] = (*fl != 0) ? ((const float*)src)[i] : bf2f(((const u16*)src)[i]);
}

// ---------------- weight prep: W[M][Kr] (flagged dtype) -> Wb bf16 [Mpad][Kpad], zero pad
__global__ __launch_bounds__(256) void k_wprep(const void* __restrict__ W, u16* __restrict__ Wb,
                                               int M, int Kr, int Kpad, int total,
                                               const u32* __restrict__ fl) {
  const int idx = blockIdx.x * 256 + threadIdx.x;
  if (idx >= total) return;
  const int m = idx / Kpad, k = idx - m * Kpad;
  u16 v = 0;
  if (m < M && k < Kr) {
    const int si = m * Kr + k;
    v = (*fl != 0) ? f2bf(((const float*)W)[si]) : ((const u16*)W)[si];
  }
  Wb[idx] = v;
}

// ---------------- LN (+optional f add), plane layout -> out [96][NPLANE] bf16
// x/f: flagged dtype with ELEMENT offset eb. grid 64 x block 256, 4 px/thread.
__global__ __launch_bounds__(256) void k_lnp(
    const void* __restrict__ x, const u32* __restrict__ xfl,
    const void* __restrict__ f, const u32* __restrict__ ffl,
    size_t eb,
    const float* __restrict__ lnw, const float* __restrict__ lnb,
    u16* __restrict__ out)
{
  const int p4 = (blockIdx.x * 256 + threadIdx.x) << 2;
  const bool xf = xfl && (*xfl != 0);
  const bool ff = ffl && (*ffl != 0);
  const size_t q0 = (eb + p4) >> 2;  // index in float4/ushort4 units along a plane row
  float s0 = 0.f, s1 = 0.f, s2 = 0.f, s3 = 0.f;
  float q0a = 0.f, q1a = 0.f, q2a = 0.f, q3a = 0.f;
  for (int c = 0; c < 96; ++c) {
    const size_t qi = q0 + ((size_t)c << 14);
    const float4 v = xf ? ((const float4*)x)[qi] : cvt4(((const ushort4*)x)[qi]);
    s0 += v.x; s1 += v.y; s2 += v.z; s3 += v.w;
    q0a += v.x * v.x; q1a += v.y * v.y; q2a += v.z * v.z; q3a += v.w * v.w;
  }
  const float m0 = s0 * (1.f / 96.f), m1 = s1 * (1.f / 96.f);
  const float m2 = s2 * (1.f / 96.f), m3 = s3 * (1.f / 96.f);
  const float r0 = rsqrtf(fmaxf(q0a * (1.f / 96.f) - m0 * m0, 0.f) + 1e-5f);
  const float r1 = rsqrtf(fmaxf(q1a * (1.f / 96.f) - m1 * m1, 0.f) + 1e-5f);
  const float r2 = rsqrtf(fmaxf(q2a * (1.f / 96.f) - m2 * m2, 0.f) + 1e-5f);
  const float r3 = rsqrtf(fmaxf(q3a * (1.f / 96.f) - m3 * m3, 0.f) + 1e-5f);
  for (int c = 0; c < 96; ++c) {
    const size_t qi = q0 + ((size_t)c << 14);
    const float4 v = xf ? ((const float4*)x)[qi] : cvt4(((const ushort4*)x)[qi]);
    const float w = lnw[c], b = lnb[c];
    float o0 = (v.x - m0) * r0 * w + b;
    float o1 = (v.y - m1) * r1 * w + b;
    float o2 = (v.z - m2) * r2 * w + b;
    float o3 = (v.w - m3) * r3 * w + b;
    if (f) {
      const float4 fv = ff ? ((const float4*)f)[qi] : cvt4(((const ushort4*)f)[qi]);
      o0 += fv.x; o1 += fv.y; o2 += fv.z; o3 += fv.w;
    }
    *(ushort4*)(out + (size_t)c * NPLANE + p4) = pack4(o0, o1, o2, o3);
  }
}

// ---------------- MFMA GEMM: out[oc][n] = sum_k Wb[oc][k] * B[k][n] (+res)
// B source: planes [K][NPLANE]; optional fused LN (+f) when lnw != null (K==96).
// Block: 256 thr (4 waves 2Mx2N), tile M=96 x N=128. grid (Mpad/96, NPLANE/128).
__global__ __launch_bounds__(256) void k_gemm(
    const void* __restrict__ xsrc, const u32* __restrict__ xfl, size_t xeb,
    const void* __restrict__ fsrc, const u32* __restrict__ ffl,
    const float* __restrict__ lnw, const float* __restrict__ lnb,
    const u16* __restrict__ Wb, int K, int Kpad, int OC,
    const void* __restrict__ res, const u32* __restrict__ rfl,
    void* __restrict__ out, const u32* __restrict__ ofl, size_t roeb)
{
  __shared__ uint4 Bt[128 * 16];
  __shared__ float mu[128], rsd[128], ps[256], pq[256];
  const int t = threadIdx.x;
  const int p = t & 127, h = t >> 7;
  const int oc0 = blockIdx.x * 96;
  const int n0 = blockIdx.y * 128;
  const int nglob = n0 + p;
  const int l = t & 63, wid = t >> 6, wm = wid >> 1, wn = wid & 1;
  const bool xf = xfl && (*xfl != 0);
  const bool LN = (lnw != nullptr);

  if (LN) {
    float s = 0.f, q = 0.f;
    const int c0 = h * 48;
    for (int c = c0; c < c0 + 48; ++c) {
      const size_t gi = xeb + (size_t)c * NPLANE + nglob;
      const float v = xf ? ((const float*)xsrc)[gi] : bf2f(((const u16*)xsrc)[gi]);
      s += v; q += v * v;
    }
    ps[t] = s; pq[t] = q;
    __syncthreads();
    if (t < 128) {
      s = ps[t] + ps[t + 128]; q = pq[t] + pq[t + 128];
      const float m = s * (1.f / 96.f);
      mu[t] = m;
      rsd[t] = rsqrtf(fmaxf(q * (1.f / 96.f) - m * m, 0.f) + 1e-5f);
    }
    __syncthreads();
  }

  f32x4 acc[3][4];
#pragma unroll
  for (int m = 0; m < 3; ++m)
#pragma unroll
    for (int n = 0; n < 4; ++n) acc[m][n] = (f32x4){0.f, 0.f, 0.f, 0.f};

  const bool ff = ffl && (*ffl != 0);
  for (int kb = 0; kb < K; kb += 128) {
    if (kb) __syncthreads();
    const int kc = min(128, K - kb);
    const int U = (kc + 7) >> 3;
    const int uh = U >> 1;
    const float lmu = LN ? mu[p] : 0.f, lrs = LN ? rsd[p] : 0.f;
    for (int j = 0; j < uh; ++j) {
      const int u = h * uh + j;
      const int cb = kb + u * 8;
      U16x8 pk;
#pragma unroll
      for (int e = 0; e < 8; ++e) {
        const int c = cb + e;
        u16 r16 = 0;
        if (c < K) {
          const size_t gi = xeb + (size_t)c * NPLANE + nglob;
          if (LN) {
            float v = xf ? ((const float*)xsrc)[gi] : bf2f(((const u16*)xsrc)[gi]);
            v = (v - lmu) * lrs * lnw[c] + lnb[c];
            if (fsrc) {
              v += ff ? ((const float*)fsrc)[gi] : bf2f(((const u16*)fsrc)[gi]);
            }
            r16 = f2bf(v);
          } else {
            r16 = ((const u16*)xsrc)[gi];
          }
        }
        pk.s[e] = r16;
      }
      Bt[p * 16 + (u ^ (p & 7))] = pk.u4;
    }
    __syncthreads();
    const int nks = (kc + 31) >> 5;
    for (int ks = 0; ks < nks; ++ks) {
      U16x8 a[3], b[4];
      const int kk = kb + ks * 32 + ((l >> 4) << 3);
#pragma unroll
      for (int m = 0; m < 3; ++m) {
        const int row = oc0 + wm * 48 + m * 16 + (l & 15);
        a[m].u4 = ((const uint4*)Wb)[((size_t)row * Kpad + kk) >> 3];
      }
#pragma unroll
      for (int ns = 0; ns < 4; ++ns) {
        const int row = wn * 64 + ns * 16 + (l & 15);
        const int up = (ks * 4 + (l >> 4)) ^ (row & 7);
        b[ns].u4 = Bt[row * 16 + up];
      }
#pragma unroll
      for (int m = 0; m < 3; ++m)
#pragma unroll
        for (int ns = 0; ns < 4; ++ns)
          acc[m][ns] = __builtin_amdgcn_mfma_f32_16x16x32_bf16(a[m].v, b[ns].v, acc[m][ns], 0, 0, 0);
    }
  }

  const bool rf = rfl && (*rfl != 0);
  const bool of = ofl && (*ofl != 0);
#pragma unroll
  for (int m = 0; m < 3; ++m) {
    const int ocb = oc0 + wm * 48 + m * 16 + ((l >> 4) << 2);
#pragma unroll
    for (int ns = 0; ns < 4; ++ns) {
      const int n = n0 + wn * 64 + ns * 16 + (l & 15);
#pragma unroll
      for (int r = 0; r < 4; ++r) {
        const int oc = ocb + r;
        if (oc < OC) {
          float v = acc[m][ns][r];
          const size_t gi = roeb + (size_t)oc * NPLANE + n;
          if (res) v += rf ? ((const float*)res)[gi] : bf2f(((const u16*)res)[gi]);
          if (of) ((float*)out)[gi] = v;
          else    ((u16*)out)[gi] = f2bf(v);
        }
      }
    }
  }
}

// ---------------- depthwise 3x3 (zero pad 1). grid (16 rowtiles, CH), block 256
__global__ __launch_bounds__(256) void k_dw(
    const u16* __restrict__ in, const float* __restrict__ w9, u16* __restrict__ out)
{
  const int c = blockIdx.y;
  const int r0 = blockIdx.x * 16;
  __shared__ float tt[18 * 256];
  const int tid = threadIdx.x;
  const u16* ip = in + (size_t)c * NPLANE;
  for (int u = tid; u < 1152; u += 256) {
    const int r = u >> 6, p4 = (u & 63) << 2;
    const int gr = r0 - 1 + r;
    float4 fv = make_float4(0.f, 0.f, 0.f, 0.f);
    if (gr >= 0 && gr < 256) fv = cvt4(*(const ushort4*)(ip + gr * 256 + p4));
    *(float4*)(tt + r * 256 + p4) = fv;
  }
  float wr[9];
#pragma unroll
  for (int i = 0; i < 9; ++i) wr[i] = w9[c * 9 + i];
  __syncthreads();
  const int col = tid;
  const bool cm = col > 0, cp = col < 255;
  float a0 = cm ? tt[col - 1] : 0.f, a1 = tt[col], a2 = cp ? tt[col + 1] : 0.f;
  float b0 = cm ? tt[256 + col - 1] : 0.f, b1 = tt[256 + col], b2 = cp ? tt[256 + col + 1] : 0.f;
  u16* op = out + (size_t)c * NPLANE + (size_t)r0 * 256 + col;
#pragma unroll
  for (int rr = 0; rr < 16; ++rr) {
    const int rn = (rr + 2) * 256;
    const float c1 = tt[rn + col];
    const float c0 = cm ? tt[rn + col - 1] : 0.f;
    const float c2 = cp ? tt[rn + col + 1] : 0.f;
    const float s = wr[0] * a0 + wr[1] * a1 + wr[2] * a2
                  + wr[3] * b0 + wr[4] * b1 + wr[5] * b2
                  + wr[6] * c0 + wr[7] * c1 + wr[8] * c2;
    op[rr * 256] = f2bf(s);
    a0 = b0; a1 = b1; a2 = b2; b0 = c0; b1 = c1; b2 = c2;
  }
}

// ---------------- depthwise 3x3 pair + gelu(x1)*x2. in: 510 planes, out: 255 planes
__global__ __launch_bounds__(256) void k_dw_gelu(
    const u16* __restrict__ in, const float* __restrict__ w9, u16* __restrict__ out)
{
  const int c = blockIdx.y;
  const int r0 = blockIdx.x * 16;
  __shared__ float t1[18 * 256];
  __shared__ float t2[18 * 256];
  const int tid = threadIdx.x;
  const u16* ip1 = in + (size_t)c * NPLANE;
  const u16* ip2 = in + (size_t)(c + 255) * NPLANE;
  for (int u = tid; u < 1152; u += 256) {
    const int r = u >> 6, p4 = (u & 63) << 2;
    const int gr = r0 - 1 + r;
    float4 fa = make_float4(0.f, 0.f, 0.f, 0.f), fb = fa;
    if (gr >= 0 && gr < 256) {
      fa = cvt4(*(const ushort4*)(ip1 + gr * 256 + p4));
      fb = cvt4(*(const ushort4*)(ip2 + gr * 256 + p4));
    }
    *(float4*)(t1 + r * 256 + p4) = fa;
    *(float4*)(t2 + r * 256 + p4) = fb;
  }
  float wa[9], wb[9];
#pragma unroll
  for (int i = 0; i < 9; ++i) { wa[i] = w9[c * 9 + i]; wb[i] = w9[(c + 255) * 9 + i]; }
  __syncthreads();
  const int col = tid;
  const bool cm = col > 0, cp = col < 255;
  float a0 = cm ? t1[col - 1] : 0.f, a1 = t1[col], a2 = cp ? t1[col + 1] : 0.f;
  float b0 = cm ? t1[256 + col - 1] : 0.f, b1 = t1[256 + col], b2 = cp ? t1[256 + col + 1] : 0.f;
  float d0 = cm ? t2[col - 1] : 0.f, d1 = t2[col], d2 = cp ? t2[col + 1] : 0.f;
  float e0 = cm ? t2[256 + col - 1] : 0.f, e1 = t2[256 + col], e2 = cp ? t2[256 + col + 1] : 0.f;
  u16* op = out + (size_t)c * NPLANE + (size_t)r0 * 256 + col;
#pragma unroll
  for (int rr = 0; rr < 16; ++rr) {
    const int rn = (rr + 2) * 256;
    const float c1 = t1[rn + col];
    const float c0 = cm ? t1[rn + col - 1] : 0.f;
    const float c2 = cp ? t1[rn + col + 1] : 0.f;
    const float g1 = wa[0] * a0 + wa[1] * a1 + wa[2] * a2
                   + wa[3] * b0 + wa[4] * b1 + wa[5] * b2
                   + wa[6] * c0 + wa[7] * c1 + wa[8] * c2;
    const float f1 = t2[rn + col];
    const float f0 = cm ? t2[rn + col - 1] : 0.f;
    const float f2 = cp ? t2[rn + col + 1] : 0.f;
    const float g2 = wb[0] * d0 + wb[1] * d1 + wb[2] * d2
                   + wb[3] * e0 + wb[4] * e1 + wb[5] * e2
                   + wb[6] * f0 + wb[7] * f1 + wb[8] * f2;
    const float gel = 0.5f * g1 * (1.f + erff(g1 * 0.70710678118654752f));
    op[rr * 256] = f2bf(gel * g2);
    a0 = b0; a1 = b1; a2 = b2; b0 = c0; b1 = c1; b2 = c2;
    d0 = e0; d1 = e1; d2 = e2; e0 = f0; e1 = f1; e2 = f2;
  }
}

// ---------------- Gram matrix S[h][i][j] + squared norms
__global__ __launch_bounds__(256) void k_reduce_s(
    const u16* __restrict__ qkv, float* __restrict__ S,
    float* __restrict__ qn2, float* __restrict__ kn2)
{
  constexpr int E = 516;
  const int h = blockIdx.y;
  const int n0 = blockIdx.x * 512;
  __shared__ __align__(16) u16 qt[16 * E];
  __shared__ __align__(16) u16 kt[16 * E];
  const int tid = threadIdx.x;
  const u16* qp = qkv + (size_t)(h * 16) * NPLANE + n0;
  const u16* kp = qkv + (size_t)(96 + h * 16) * NPLANE + n0;
#pragma unroll
  for (int i = 0; i < 8; ++i) {
    const int u = tid + i * 256;
    const int r = u >> 7, p4 = (u & 127) << 2;
    *(ushort4*)(qt + r * E + p4) = *(const ushort4*)(qp + (size_t)r * NPLANE + p4);
    *(ushort4*)(kt + r * E + p4) = *(const ushort4*)(kp + (size_t)r * NPLANE + p4);
  }
  __syncthreads();
  {
    const int s = tid >> 6, i2 = (tid >> 3) & 7, j2 = tid & 7;
    const int i = i2 * 2, j = j2 * 2;
    const u32* q0r = (const u32*)(qt + i * E);
    const u32* q1r = (const u32*)(qt + (i + 1) * E);
    const u32* k0r = (const u32*)(kt + j * E);
    const u32* k1r = (const u32*)(kt + (j + 1) * E);
    float a00 = 0.f, a01 = 0.f, a10 = 0.f, a11 = 0.f;
    const int d0 = s * 64;
#pragma unroll 4
    for (int d = d0; d < d0 + 64; ++d) {
      const u32 qv0 = q0r[d], qv1 = q1r[d], kv0 = k0r[d], kv1 = k1r[d];
      const float qa = lo2f(qv0), qbv = hi2f(qv0);
      const float pa = lo2f(qv1), pb = hi2f(qv1);
      const float ka = lo2f(kv0), kb = hi2f(kv0);
      const float la = lo2f(kv1), lb = hi2f(kv1);
      a00 += qa * ka + qbv * kb;
      a01 += qa * la + qbv * lb;
      a10 += pa * ka + pb * kb;
      a11 += pa * la + pb * lb;
    }
    float* Sh = S + h * 256;
    atomicAdd(Sh + i * 16 + j, a00);
    atomicAdd(Sh + i * 16 + j + 1, a01);
    atomicAdd(Sh + (i + 1) * 16 + j, a10);
    atomicAdd(Sh + (i + 1) * 16 + j + 1, a11);
  }
  if (tid < 128) {
    const int isK = tid >> 6;
    const int t2 = tid & 63;
    const int ii = t2 & 15, ss = t2 >> 4;
    const u32* rr = (const u32*)((isK ? kt : qt) + ii * E);
    float ns = 0.f;
    const int d0 = ss * 64;
#pragma unroll 4
    for (int d = d0; d < d0 + 64; ++d) {
      const u32 v = rr[d];
      const float x0 = lo2f(v), x1 = hi2f(v);
      ns += x0 * x0 + x1 * x1;
    }
    atomicAdd((isK ? kn2 : qn2) + h * 16 + ii, ns);
  }
}

// ---------------- softmax + fold proj -> Mtb bf16 [e][dg] (96x96)
__global__ __launch_bounds__(256) void k_softmax_m(
    const float* __restrict__ S, const float* __restrict__ qn2, const float* __restrict__ kn2,
    const float* __restrict__ temp, const float* __restrict__ proj, u16* __restrict__ Mtb)
{
  __shared__ float attn[6 * 256];
  const int tid = threadIdx.x;
  if (tid < 96) {
    const int h = tid >> 4, i = tid & 15;
    const float qn = fmaxf(sqrtf(qn2[tid]), 1e-12f);
    const float tp = temp[h];
    float row[16];
    float mx = -3.4e38f;
#pragma unroll
    for (int d = 0; d < 16; ++d) {
      const float kn = fmaxf(sqrtf(kn2[h * 16 + d]), 1e-12f);
      row[d] = S[h * 256 + i * 16 + d] / (qn * kn) * tp;
      mx = fmaxf(mx, row[d]);
    }
    float sum = 0.f;
#pragma unroll
    for (int d = 0; d < 16; ++d) { row[d] = expf(row[d] - mx); sum += row[d]; }
    const float inv = 1.f / sum;
#pragma unroll
    for (int d = 0; d < 16; ++d) attn[h * 256 + i * 16 + d] = row[d] * inv;
  }
  __syncthreads();
  for (int u = tid; u < 9216; u += 256) {
    const int e = u / 96, dg = u - e * 96;
    const int h = dg >> 4, d = dg & 15;
    float s = 0.f;
#pragma unroll
    for (int i = 0; i < 16; ++i)
      s += proj[e * 96 + h * 16 + i] * attn[h * 256 + i * 16 + d];
    Mtb[u] = f2bf(s);
  }
}

extern "C" void kernel_launch(void* const* d_in, const int* in_sizes, int n_in,
                              void* d_out, int out_size, void* d_ws, size_t ws_size,
                              hipStream_t stream)
{
  (void)in_sizes; (void)n_in; (void)out_size;
  if (ws_size < (size_t)130400000) return;

  const void* Fw  = d_in[0];
  const void* F0c = d_in[1];
  const void* Kdi = d_in[2];

  char* ws = (char*)d_ws;
  u16* xcur = (u16*)ws;
  u16* bufA = (u16*)(ws + 25165824);
  u16* bufB = (u16*)(ws + 92012544);
  u16* wb   = (u16*)(ws + 129761280);
  u16* Wq1 = wb;           u16* Wi1 = wb + 27648;   u16* Wo1 = wb + 82944;
  u16* Wq2 = wb + 107520;  u16* Wi2 = wb + 135168;  u16* Wo2 = wb + 190464;
  u16* Mtb = wb + 215040;  // 96x96
  float* fz = (float*)(ws + 130209792);
  float* dwA1 = fz;          float* dwF1 = fz + 2592;
  float* dwA2 = fz + 7182;   float* dwF2 = fz + 9774;
  float* prj1 = fz + 14364;  float* prj2 = fz + 23580;
  float* tmp1 = fz + 32796;  float* tmp2 = fz + 32802;
  float* lnp  = fz + 32808;  // 8 x 96
  float* Sb   = fz + 33576;  float* Qn = fz + 35112;  float* Kn = fz + 35208;
  u32*  flag  = (u32*)(fz + 35304);

  k_detect<<<1, 64, 0, stream>>>((const u16*)d_in[3], flag);

  k_wprep<<<dim3(108), 256, 0, stream>>>(d_in[5],  Wq1, 288, 96, 96,  27648, flag);
  k_wprep<<<dim3(216), 256, 0, stream>>>(d_in[11], Wi1, 510, 96, 96,  55296, flag);
  k_wprep<<<dim3(96),  256, 0, stream>>>(d_in[13], Wo1, 96,  255, 256, 24576, flag);
  k_wprep<<<dim3(108), 256, 0, stream>>>(d_in[16], Wq2, 288, 96, 96,  27648, flag);
  k_wprep<<<dim3(216), 256, 0, stream>>>(d_in[22], Wi2, 510, 96, 96,  55296, flag);
  k_wprep<<<dim3(96),  256, 0, stream>>>(d_in[24], Wo2, 96,  255, 256, 24576, flag);

  k_cvt_f32<<<dim3(11), 256, 0, stream>>>(d_in[6],  dwA1, 2592, flag);
  k_cvt_f32<<<dim3(18), 256, 0, stream>>>(d_in[12], dwF1, 4590, flag);
  k_cvt_f32<<<dim3(11), 256, 0, stream>>>(d_in[17], dwA2, 2592, flag);
  k_cvt_f32<<<dim3(18), 256, 0, stream>>>(d_in[23], dwF2, 4590, flag);
  k_cvt_f32<<<dim3(36), 256, 0, stream>>>(d_in[7],  prj1, 9216, flag);
  k_cvt_f32<<<dim3(36), 256, 0, stream>>>(d_in[18], prj2, 9216, flag);
  k_cvt_f32<<<dim3(1), 256, 0, stream>>>(d_in[8],  tmp1, 6, flag);
  k_cvt_f32<<<dim3(1), 256, 0, stream>>>(d_in[19], tmp2, 6, flag);
  k_cvt_f32<<<dim3(1), 256, 0, stream>>>(d_in[3],  lnp + 0,   96, flag);
  k_cvt_f32<<<dim3(1), 256, 0, stream>>>(d_in[4],  lnp + 96,  96, flag);
  k_cvt_f32<<<dim3(1), 256, 0, stream>>>(d_in[9],  lnp + 192, 96, flag);
  k_cvt_f32<<<dim3(1), 256, 0, stream>>>(d_in[10], lnp + 288, 96, flag);
  k_cvt_f32<<<dim3(1), 256, 0, stream>>>(d_in[14], lnp + 384, 96, flag);
  k_cvt_f32<<<dim3(1), 256, 0, stream>>>(d_in[15], lnp + 480, 96, flag);
  k_cvt_f32<<<dim3(1), 256, 0, stream>>>(d_in[20], lnp + 576, 96, flag);
  k_cvt_f32<<<dim3(1), 256, 0, stream>>>(d_in[21], lnp + 672, 96, flag);

  // attn: out = res + proj(attn(dw(conv(LN(x)+f))))
  auto attn_stage = [&](const void* x, const u32* xfl, const void* f, const u32* ffl,
                        const float* lw, const float* lb, const u16* Wq,
                        const float* dwf, const float* tmpf, const float* prjf,
                        const void* res, const u32* rfl,
                        void* outx, const u32* ofl) {
    for (int b = 0; b < 2; ++b) {
      const size_t eb = (size_t)b * BELEMS;
      hipMemsetAsync(Sb, 0, 1728 * sizeof(float), stream);
      k_lnp<<<dim3(64), 256, 0, stream>>>(x, xfl, f, ffl, eb, lw, lb, bufB);
      k_gemm<<<dim3(3, 512), 256, 0, stream>>>(bufB, nullptr, 0, nullptr, nullptr,
                                               nullptr, nullptr,
                                               Wq, 96, 96, 288,
                                               nullptr, nullptr, bufA, nullptr, 0);
      k_dw<<<dim3(16, 288), 256, 0, stream>>>(bufA, dwf, bufB);
      k_reduce_s<<<dim3(128, 6), 256, 0, stream>>>(bufB, Sb, Qn, Kn);
      k_softmax_m<<<dim3(1), 256, 0, stream>>>(Sb, Qn, Kn, tmpf, prjf, Mtb);
      k_gemm<<<dim3(1, 512), 256, 0, stream>>>(bufB + (size_t)192 * NPLANE, nullptr, 0,
                                               nullptr, nullptr, nullptr, nullptr,
                                               Mtb, 96, 96, 96,
                                               res, rfl, outx, ofl, eb);
    }
  };
  auto ffn_stage = [&](const void* x, const u32* xfl,
                       const float* lw, const float* lb, const u16* Wi,
                       const float* dwf, const u16* Wo,
                       void* outx, const u32* ofl) {
    for (int b = 0; b < 2; ++b) {
      const size_t eb = (size_t)b * BELEMS;
      k_lnp<<<dim3(64), 256, 0, stream>>>(x, xfl, nullptr, nullptr, eb, lw, lb, bufB);
      k_gemm<<<dim3(6, 512), 256, 0, stream>>>(bufB, nullptr, 0, nullptr, nullptr,
                                               nullptr, nullptr,
                                               Wi, 96, 96, 510,
                                               nullptr, nullptr, bufA, nullptr, 0);
      k_dw_gelu<<<dim3(16, 255), 256, 0, stream>>>(bufA, dwf, bufB);
      k_gemm<<<dim3(1, 512), 256, 0, stream>>>(bufB, nullptr, 0,
                                               nullptr, nullptr, nullptr, nullptr,
                                               Wo, 255, 256, 96,
                                               x, xfl, outx, ofl, eb);
    }
  };

  // stage 1: x1 = Fw + attn(LN1(Fw) + F0c)
  attn_stage(Fw, flag, F0c, flag, lnp + 0, lnp + 96, Wq1, dwA1, tmp1, prj1,
             Fw, flag, xcur, nullptr);
  // stage 2: x2 = x1 + ffn(LN2(x1))
  ffn_stage(xcur, nullptr, lnp + 192, lnp + 288, Wi1, dwF1, Wo1, xcur, nullptr);
  // stage 3: x3 = x2 + attn(LN3(x2) + Kd)
  attn_stage(xcur, nullptr, Kdi, flag, lnp + 384, lnp + 480, Wq2, dwA2, tmp2, prj2,
             xcur, nullptr, xcur, nullptr);
  // stage 4: out = x3 + ffn(LN4(x3))
  ffn_stage(xcur, nullptr, lnp + 576, lnp + 672, Wi2, dwF2, Wo2, d_out, flag);
}

// Round 7
// 1230.163 us; speedup vs baseline: 1.5042x; 1.5042x over previous
//
#include <hip/hip_runtime.h>
#include <math.h>

using u16 = unsigned short;
using u32 = unsigned int;
typedef __attribute__((ext_vector_type(8))) short bf16x8;
typedef __attribute__((ext_vector_type(4))) float f32x4;

#define NPLANE 65536
#define BELEMS ((size_t)6291456) /* 96*65536 elements per batch */

__device__ __forceinline__ float bf2f(u16 u) { return __uint_as_float(((u32)u) << 16); }
__device__ __forceinline__ float lo2f(u32 v) { return __uint_as_float(v << 16); }
__device__ __forceinline__ float hi2f(u32 v) { return __uint_as_float(v & 0xffff0000u); }
__device__ __forceinline__ u16 f2bf(float f) {
  if (!__builtin_isfinite(f)) return (u16)0x5F80;  // diagnostic sentinel ~1.8e19
  u32 u = __float_as_uint(f);
  return (u16)((u + 0x7fffu + ((u >> 16) & 1u)) >> 16);
}
__device__ __forceinline__ float4 cvt4(ushort4 v) {
  return make_float4(bf2f(v.x), bf2f(v.y), bf2f(v.z), bf2f(v.w));
}
__device__ __forceinline__ ushort4 pack4(float a, float b, float c, float d) {
  ushort4 o; o.x = f2bf(a); o.y = f2bf(b); o.z = f2bf(c); o.w = f2bf(d); return o;
}

union U16x8 { uint4 u4; bf16x8 v; u16 s[8]; };

// ---------------- dtype detect: ln1_w[0] == 1.0. bf16 -> 0x3F80, fp32 low half -> 0x0000
__global__ void k_detect(const u16* __restrict__ p, u32* __restrict__ flag) {
  if (blockIdx.x == 0 && threadIdx.x == 0) *flag = (p[0] == (u16)0x3F80) ? 0u : 1u;
}

// ---------------- small param convert -> f32
__global__ __launch_bounds__(256) void k_cvt_f32(const void* __restrict__ src,
                                                 float* __restrict__ dst, int n,
                                                 const u32* __restrict__ fl) {
  const int i = blockIdx.x * 256 + threadIdx.x;
  if (i >= n) return;
  dst[i] = (*fl != 0) ? ((const float*)src)[i] : bf2f(((const u16*)src)[i]);
}

// ---------------- weight prep: W[M][Kr] (flagged dtype) -> Wb bf16 [Mpad][Kpad], zero pad
__global__ __launch_bounds__(256) void k_wprep(const void* __restrict__ W, u16* __restrict__ Wb,
                                               int M, int Kr, int Kpad, int total,
                                               const u32* __restrict__ fl) {
  const int idx = blockIdx.x * 256 + threadIdx.x;
  if (idx >= total) return;
  const int m = idx / Kpad, k = idx - m * Kpad;
  u16 v = 0;
  if (m < M && k < Kr) {
    const int si = m * Kr + k;
    v = (*fl != 0) ? f2bf(((const float*)W)[si]) : ((const u16*)W)[si];
  }
  Wb[idx] = v;
}

// ---------------- LN (+optional f add), tiled: 96ch x 64px per block -> plane bf16
// grid 1024, block 256. Coalesced vector loads, LDS staging, 16 waves/CU.
__global__ __launch_bounds__(256) void k_lnp(
    const void* __restrict__ x, const u32* __restrict__ xfl,
    const void* __restrict__ f, const u32* __restrict__ ffl,
    size_t eb,
    const float* __restrict__ lnw, const float* __restrict__ lnb,
    u16* __restrict__ out)
{
  __shared__ float xin[96 * 64];
  __shared__ float fin[96 * 64];
  __shared__ float ps[256], pq[256];
  __shared__ float mu[64], rsd[64];
  const int tid = threadIdx.x;
  const int pix0 = blockIdx.x * 64;
  const bool xf = xfl && (*xfl != 0);
  const bool ff = ffl && (*ffl != 0);

#pragma unroll
  for (int i = 0; i < 6; ++i) {
    const int u = tid + i * 256;
    const int c = u >> 4, p4 = (u & 15) << 2;
    const size_t base = eb + (size_t)c * NPLANE + pix0 + p4;
    const float4 v = xf ? *(const float4*)((const float*)x + base)
                        : cvt4(*(const ushort4*)((const u16*)x + base));
    *(float4*)(xin + c * 64 + p4) = v;
    if (f) {
      const float4 fv = ff ? *(const float4*)((const float*)f + base)
                           : cvt4(*(const ushort4*)((const u16*)f + base));
      *(float4*)(fin + c * 64 + p4) = fv;
    }
  }
  __syncthreads();
  {
    const int p = tid & 63, qq = tid >> 6;
    float s = 0.f, q = 0.f;
    const int c0 = qq * 24;
#pragma unroll 8
    for (int c = c0; c < c0 + 24; ++c) {
      const float v = xin[c * 64 + p];
      s += v; q += v * v;
    }
    ps[tid] = s; pq[tid] = q;
  }
  __syncthreads();
  if (tid < 64) {
    const float s = ps[tid] + ps[tid + 64] + ps[tid + 128] + ps[tid + 192];
    const float q = pq[tid] + pq[tid + 64] + pq[tid + 128] + pq[tid + 192];
    const float m = s * (1.f / 96.f);
    mu[tid] = m;
    rsd[tid] = rsqrtf(fmaxf(q * (1.f / 96.f) - m * m, 0.f) + 1e-5f);
  }
  __syncthreads();
#pragma unroll
  for (int i = 0; i < 6; ++i) {
    const int u = tid + i * 256;
    const int c = u >> 4, p4 = (u & 15) << 2;
    const float4 v = *(const float4*)(xin + c * 64 + p4);
    const float w = lnw[c], b = lnb[c];
    float o0 = (v.x - mu[p4 + 0]) * rsd[p4 + 0] * w + b;
    float o1 = (v.y - mu[p4 + 1]) * rsd[p4 + 1] * w + b;
    float o2 = (v.z - mu[p4 + 2]) * rsd[p4 + 2] * w + b;
    float o3 = (v.w - mu[p4 + 3]) * rsd[p4 + 3] * w + b;
    if (f) {
      const float4 fv = *(const float4*)(fin + c * 64 + p4);
      o0 += fv.x; o1 += fv.y; o2 += fv.z; o3 += fv.w;
    }
    *(ushort4*)(out + (size_t)c * NPLANE + pix0 + p4) = pack4(o0, o1, o2, o3);
  }
}

// ---------------- MFMA GEMM: out[oc][n] = sum_k Wb[oc][k] * B[k][n] (+res)
// B source: planes [K][NPLANE]; optional fused LN (+f) when lnw != null (K==96).
// Block: 256 thr (4 waves 2Mx2N), tile M=96 x N=128. grid (Mpad/96, NPLANE/128).
__global__ __launch_bounds__(256) void k_gemm(
    const void* __restrict__ xsrc, const u32* __restrict__ xfl, size_t xeb,
    const void* __restrict__ fsrc, const u32* __restrict__ ffl,
    const float* __restrict__ lnw, const float* __restrict__ lnb,
    const u16* __restrict__ Wb, int K, int Kpad, int OC,
    const void* __restrict__ res, const u32* __restrict__ rfl,
    void* __restrict__ out, const u32* __restrict__ ofl, size_t roeb)
{
  __shared__ uint4 Bt[128 * 16];
  __shared__ float mu[128], rsd[128], ps[256], pq[256];
  const int t = threadIdx.x;
  const int p = t & 127, h = t >> 7;
  const int oc0 = blockIdx.x * 96;
  const int n0 = blockIdx.y * 128;
  const int nglob = n0 + p;
  const int l = t & 63, wid = t >> 6, wm = wid >> 1, wn = wid & 1;
  const bool xf = xfl && (*xfl != 0);
  const bool LN = (lnw != nullptr);

  if (LN) {
    float s = 0.f, q = 0.f;
    const int c0 = h * 48;
    for (int c = c0; c < c0 + 48; ++c) {
      const size_t gi = xeb + (size_t)c * NPLANE + nglob;
      const float v = xf ? ((const float*)xsrc)[gi] : bf2f(((const u16*)xsrc)[gi]);
      s += v; q += v * v;
    }
    ps[t] = s; pq[t] = q;
    __syncthreads();
    if (t < 128) {
      s = ps[t] + ps[t + 128]; q = pq[t] + pq[t + 128];
      const float m = s * (1.f / 96.f);
      mu[t] = m;
      rsd[t] = rsqrtf(fmaxf(q * (1.f / 96.f) - m * m, 0.f) + 1e-5f);
    }
    __syncthreads();
  }

  f32x4 acc[3][4];
#pragma unroll
  for (int m = 0; m < 3; ++m)
#pragma unroll
    for (int n = 0; n < 4; ++n) acc[m][n] = (f32x4){0.f, 0.f, 0.f, 0.f};

  const bool ff = ffl && (*ffl != 0);
  for (int kb = 0; kb < K; kb += 128) {
    if (kb) __syncthreads();
    const int kc = min(128, K - kb);
    const int U = (kc + 7) >> 3;
    const int uh = U >> 1;
    const float lmu = LN ? mu[p] : 0.f, lrs = LN ? rsd[p] : 0.f;
    for (int j = 0; j < uh; ++j) {
      const int u = h * uh + j;
      const int cb = kb + u * 8;
      U16x8 pk;
#pragma unroll
      for (int e = 0; e < 8; ++e) {
        const int c = cb + e;
        u16 r16 = 0;
        if (c < K) {
          const size_t gi = xeb + (size_t)c * NPLANE + nglob;
          if (LN) {
            float v = xf ? ((const float*)xsrc)[gi] : bf2f(((const u16*)xsrc)[gi]);
            v = (v - lmu) * lrs * lnw[c] + lnb[c];
            if (fsrc) {
              v += ff ? ((const float*)fsrc)[gi] : bf2f(((const u16*)fsrc)[gi]);
            }
            r16 = f2bf(v);
          } else {
            r16 = ((const u16*)xsrc)[gi];
          }
        }
        pk.s[e] = r16;
      }
      Bt[p * 16 + (u ^ (p & 7))] = pk.u4;
    }
    __syncthreads();
    const int nks = (kc + 31) >> 5;
    for (int ks = 0; ks < nks; ++ks) {
      U16x8 a[3], b[4];
      const int kk = kb + ks * 32 + ((l >> 4) << 3);
#pragma unroll
      for (int m = 0; m < 3; ++m) {
        const int row = oc0 + wm * 48 + m * 16 + (l & 15);
        a[m].u4 = ((const uint4*)Wb)[((size_t)row * Kpad + kk) >> 3];
      }
#pragma unroll
      for (int ns = 0; ns < 4; ++ns) {
        const int row = wn * 64 + ns * 16 + (l & 15);
        const int up = (ks * 4 + (l >> 4)) ^ (row & 7);
        b[ns].u4 = Bt[row * 16 + up];
      }
#pragma unroll
      for (int m = 0; m < 3; ++m)
#pragma unroll
        for (int ns = 0; ns < 4; ++ns)
          acc[m][ns] = __builtin_amdgcn_mfma_f32_16x16x32_bf16(a[m].v, b[ns].v, acc[m][ns], 0, 0, 0);
    }
  }

  const bool rf = rfl && (*rfl != 0);
  const bool of = ofl && (*ofl != 0);
#pragma unroll
  for (int m = 0; m < 3; ++m) {
    const int ocb = oc0 + wm * 48 + m * 16 + ((l >> 4) << 2);
#pragma unroll
    for (int ns = 0; ns < 4; ++ns) {
      const int n = n0 + wn * 64 + ns * 16 + (l & 15);
#pragma unroll
      for (int r = 0; r < 4; ++r) {
        const int oc = ocb + r;
        if (oc < OC) {
          float v = acc[m][ns][r];
          const size_t gi = roeb + (size_t)oc * NPLANE + n;
          if (res) v += rf ? ((const float*)res)[gi] : bf2f(((const u16*)res)[gi]);
          if (of) ((float*)out)[gi] = v;
          else    ((u16*)out)[gi] = f2bf(v);
        }
      }
    }
  }
}

// ---------------- depthwise 3x3 (zero pad 1). grid (16 rowtiles, CH), block 256
__global__ __launch_bounds__(256) void k_dw(
    const u16* __restrict__ in, const float* __restrict__ w9, u16* __restrict__ out)
{
  const int c = blockIdx.y;
  const int r0 = blockIdx.x * 16;
  __shared__ float tt[18 * 256];
  const int tid = threadIdx.x;
  const u16* ip = in + (size_t)c * NPLANE;
  for (int u = tid; u < 1152; u += 256) {
    const int r = u >> 6, p4 = (u & 63) << 2;
    const int gr = r0 - 1 + r;
    float4 fv = make_float4(0.f, 0.f, 0.f, 0.f);
    if (gr >= 0 && gr < 256) fv = cvt4(*(const ushort4*)(ip + gr * 256 + p4));
    *(float4*)(tt + r * 256 + p4) = fv;
  }
  float wr[9];
#pragma unroll
  for (int i = 0; i < 9; ++i) wr[i] = w9[c * 9 + i];
  __syncthreads();
  const int col = tid;
  const bool cm = col > 0, cp = col < 255;
  float a0 = cm ? tt[col - 1] : 0.f, a1 = tt[col], a2 = cp ? tt[col + 1] : 0.f;
  float b0 = cm ? tt[256 + col - 1] : 0.f, b1 = tt[256 + col], b2 = cp ? tt[256 + col + 1] : 0.f;
  u16* op = out + (size_t)c * NPLANE + (size_t)r0 * 256 + col;
#pragma unroll
  for (int rr = 0; rr < 16; ++rr) {
    const int rn = (rr + 2) * 256;
    const float c1 = tt[rn + col];
    const float c0 = cm ? tt[rn + col - 1] : 0.f;
    const float c2 = cp ? tt[rn + col + 1] : 0.f;
    const float s = wr[0] * a0 + wr[1] * a1 + wr[2] * a2
                  + wr[3] * b0 + wr[4] * b1 + wr[5] * b2
                  + wr[6] * c0 + wr[7] * c1 + wr[8] * c2;
    op[rr * 256] = f2bf(s);
    a0 = b0; a1 = b1; a2 = b2; b0 = c0; b1 = c1; b2 = c2;
  }
}

// ---------------- depthwise 3x3 pair + gelu(x1)*x2. in: 510 planes, out: 255 planes
__global__ __launch_bounds__(256) void k_dw_gelu(
    const u16* __restrict__ in, const float* __restrict__ w9, u16* __restrict__ out)
{
  const int c = blockIdx.y;
  const int r0 = blockIdx.x * 16;
  __shared__ float t1[18 * 256];
  __shared__ float t2[18 * 256];
  const int tid = threadIdx.x;
  const u16* ip1 = in + (size_t)c * NPLANE;
  const u16* ip2 = in + (size_t)(c + 255) * NPLANE;
  for (int u = tid; u < 1152; u += 256) {
    const int r = u >> 6, p4 = (u & 63) << 2;
    const int gr = r0 - 1 + r;
    float4 fa = make_float4(0.f, 0.f, 0.f, 0.f), fb = fa;
    if (gr >= 0 && gr < 256) {
      fa = cvt4(*(const ushort4*)(ip1 + gr * 256 + p4));
      fb = cvt4(*(const ushort4*)(ip2 + gr * 256 + p4));
    }
    *(float4*)(t1 + r * 256 + p4) = fa;
    *(float4*)(t2 + r * 256 + p4) = fb;
  }
  float wa[9], wb[9];
#pragma unroll
  for (int i = 0; i < 9; ++i) { wa[i] = w9[c * 9 + i]; wb[i] = w9[(c + 255) * 9 + i]; }
  __syncthreads();
  const int col = tid;
  const bool cm = col > 0, cp = col < 255;
  float a0 = cm ? t1[col - 1] : 0.f, a1 = t1[col], a2 = cp ? t1[col + 1] : 0.f;
  float b0 = cm ? t1[256 + col - 1] : 0.f, b1 = t1[256 + col], b2 = cp ? t1[256 + col + 1] : 0.f;
  float d0 = cm ? t2[col - 1] : 0.f, d1 = t2[col], d2 = cp ? t2[col + 1] : 0.f;
  float e0 = cm ? t2[256 + col - 1] : 0.f, e1 = t2[256 + col], e2 = cp ? t2[256 + col + 1] : 0.f;
  u16* op = out + (size_t)c * NPLANE + (size_t)r0 * 256 + col;
#pragma unroll
  for (int rr = 0; rr < 16; ++rr) {
    const int rn = (rr + 2) * 256;
    const float c1 = t1[rn + col];
    const float c0 = cm ? t1[rn + col - 1] : 0.f;
    const float c2 = cp ? t1[rn + col + 1] : 0.f;
    const float g1 = wa[0] * a0 + wa[1] * a1 + wa[2] * a2
                   + wa[3] * b0 + wa[4] * b1 + wa[5] * b2
                   + wa[6] * c0 + wa[7] * c1 + wa[8] * c2;
    const float f1 = t2[rn + col];
    const float f0 = cm ? t2[rn + col - 1] : 0.f;
    const float f2 = cp ? t2[rn + col + 1] : 0.f;
    const float g2 = wb[0] * d0 + wb[1] * d1 + wb[2] * d2
                   + wb[3] * e0 + wb[4] * e1 + wb[5] * e2
                   + wb[6] * f0 + wb[7] * f1 + wb[8] * f2;
    const float gel = 0.5f * g1 * (1.f + erff(g1 * 0.70710678118654752f));
    op[rr * 256] = f2bf(gel * g2);
    a0 = b0; a1 = b1; a2 = b2; b0 = c0; b1 = c1; b2 = c2;
    d0 = e0; d1 = e1; d2 = e2; e0 = f0; e1 = f1; e2 = f2;
  }
}

// ---------------- Gram matrix S[h][i][j] + squared norms
__global__ __launch_bounds__(256) void k_reduce_s(
    const u16* __restrict__ qkv, float* __restrict__ S,
    float* __restrict__ qn2, float* __restrict__ kn2)
{
  constexpr int E = 516;
  const int h = blockIdx.y;
  const int n0 = blockIdx.x * 512;
  __shared__ __align__(16) u16 qt[16 * E];
  __shared__ __align__(16) u16 kt[16 * E];
  const int tid = threadIdx.x;
  const u16* qp = qkv + (size_t)(h * 16) * NPLANE + n0;
  const u16* kp = qkv + (size_t)(96 + h * 16) * NPLANE + n0;
#pragma unroll
  for (int i = 0; i < 8; ++i) {
    const int u = tid + i * 256;
    const int r = u >> 7, p4 = (u & 127) << 2;
    *(ushort4*)(qt + r * E + p4) = *(const ushort4*)(qp + (size_t)r * NPLANE + p4);
    *(ushort4*)(kt + r * E + p4) = *(const ushort4*)(kp + (size_t)r * NPLANE + p4);
  }
  __syncthreads();
  {
    const int s = tid >> 6, i2 = (tid >> 3) & 7, j2 = tid & 7;
    const int i = i2 * 2, j = j2 * 2;
    const u32* q0r = (const u32*)(qt + i * E);
    const u32* q1r = (const u32*)(qt + (i + 1) * E);
    const u32* k0r = (const u32*)(kt + j * E);
    const u32* k1r = (const u32*)(kt + (j + 1) * E);
    float a00 = 0.f, a01 = 0.f, a10 = 0.f, a11 = 0.f;
    const int d0 = s * 64;
#pragma unroll 4
    for (int d = d0; d < d0 + 64; ++d) {
      const u32 qv0 = q0r[d], qv1 = q1r[d], kv0 = k0r[d], kv1 = k1r[d];
      const float qa = lo2f(qv0), qbv = hi2f(qv0);
      const float pa = lo2f(qv1), pb = hi2f(qv1);
      const float ka = lo2f(kv0), kb = hi2f(kv0);
      const float la = lo2f(kv1), lb = hi2f(kv1);
      a00 += qa * ka + qbv * kb;
      a01 += qa * la + qbv * lb;
      a10 += pa * ka + pb * kb;
      a11 += pa * la + pb * lb;
    }
    float* Sh = S + h * 256;
    atomicAdd(Sh + i * 16 + j, a00);
    atomicAdd(Sh + i * 16 + j + 1, a01);
    atomicAdd(Sh + (i + 1) * 16 + j, a10);
    atomicAdd(Sh + (i + 1) * 16 + j + 1, a11);
  }
  if (tid < 128) {
    const int isK = tid >> 6;
    const int t2 = tid & 63;
    const int ii = t2 & 15, ss = t2 >> 4;
    const u32* rr = (const u32*)((isK ? kt : qt) + ii * E);
    float ns = 0.f;
    const int d0 = ss * 64;
#pragma unroll 4
    for (int d = d0; d < d0 + 64; ++d) {
      const u32 v = rr[d];
      const float x0 = lo2f(v), x1 = hi2f(v);
      ns += x0 * x0 + x1 * x1;
    }
    atomicAdd((isK ? kn2 : qn2) + h * 16 + ii, ns);
  }
}

// ---------------- softmax + fold proj -> Mtb bf16 [e][dg] (96x96)
__global__ __launch_bounds__(256) void k_softmax_m(
    const float* __restrict__ S, const float* __restrict__ qn2, const float* __restrict__ kn2,
    const float* __restrict__ temp, const float* __restrict__ proj, u16* __restrict__ Mtb)
{
  __shared__ float attn[6 * 256];
  const int tid = threadIdx.x;
  if (tid < 96) {
    const int h = tid >> 4, i = tid & 15;
    const float qn = fmaxf(sqrtf(qn2[tid]), 1e-12f);
    const float tp = temp[h];
    float row[16];
    float mx = -3.4e38f;
#pragma unroll
    for (int d = 0; d < 16; ++d) {
      const float kn = fmaxf(sqrtf(kn2[h * 16 + d]), 1e-12f);
      row[d] = S[h * 256 + i * 16 + d] / (qn * kn) * tp;
      mx = fmaxf(mx, row[d]);
    }
    float sum = 0.f;
#pragma unroll
    for (int d = 0; d < 16; ++d) { row[d] = expf(row[d] - mx); sum += row[d]; }
    const float inv = 1.f / sum;
#pragma unroll
    for (int d = 0; d < 16; ++d) attn[h * 256 + i * 16 + d] = row[d] * inv;
  }
  __syncthreads();
  for (int u = tid; u < 9216; u += 256) {
    const int e = u / 96, dg = u - e * 96;
    const int h = dg >> 4, d = dg & 15;
    float s = 0.f;
#pragma unroll
    for (int i = 0; i < 16; ++i)
      s += proj[e * 96 + h * 16 + i] * attn[h * 256 + i * 16 + d];
    Mtb[u] = f2bf(s);
  }
}

extern "C" void kernel_launch(void* const* d_in, const int* in_sizes, int n_in,
                              void* d_out, int out_size, void* d_ws, size_t ws_size,
                              hipStream_t stream)
{
  (void)in_sizes; (void)n_in; (void)out_size;
  if (ws_size < (size_t)130400000) return;

  const void* Fw  = d_in[0];
  const void* F0c = d_in[1];
  const void* Kdi = d_in[2];

  char* ws = (char*)d_ws;
  u16* xcur = (u16*)ws;
  u16* bufA = (u16*)(ws + 25165824);
  u16* bufB = (u16*)(ws + 92012544);
  u16* wb   = (u16*)(ws + 129761280);
  u16* Wq1 = wb;           u16* Wi1 = wb + 27648;   u16* Wo1 = wb + 82944;
  u16* Wq2 = wb + 107520;  u16* Wi2 = wb + 135168;  u16* Wo2 = wb + 190464;
  u16* Mtb = wb + 215040;  // 96x96
  float* fz = (float*)(ws + 130209792);
  float* dwA1 = fz;          float* dwF1 = fz + 2592;
  float* dwA2 = fz + 7182;   float* dwF2 = fz + 9774;
  float* prj1 = fz + 14364;  float* prj2 = fz + 23580;
  float* tmp1 = fz + 32796;  float* tmp2 = fz + 32802;
  float* lnp  = fz + 32808;  // 8 x 96
  float* Sb   = fz + 33576;  float* Qn = fz + 35112;  float* Kn = fz + 35208;
  u32*  flag  = (u32*)(fz + 35304);

  k_detect<<<1, 64, 0, stream>>>((const u16*)d_in[3], flag);

  k_wprep<<<dim3(108), 256, 0, stream>>>(d_in[5],  Wq1, 288, 96, 96,  27648, flag);
  k_wprep<<<dim3(216), 256, 0, stream>>>(d_in[11], Wi1, 510, 96, 96,  55296, flag);
  k_wprep<<<dim3(96),  256, 0, stream>>>(d_in[13], Wo1, 96,  255, 256, 24576, flag);
  k_wprep<<<dim3(108), 256, 0, stream>>>(d_in[16], Wq2, 288, 96, 96,  27648, flag);
  k_wprep<<<dim3(216), 256, 0, stream>>>(d_in[22], Wi2, 510, 96, 96,  55296, flag);
  k_wprep<<<dim3(96),  256, 0, stream>>>(d_in[24], Wo2, 96,  255, 256, 24576, flag);

  k_cvt_f32<<<dim3(11), 256, 0, stream>>>(d_in[6],  dwA1, 2592, flag);
  k_cvt_f32<<<dim3(18), 256, 0, stream>>>(d_in[12], dwF1, 4590, flag);
  k_cvt_f32<<<dim3(11), 256, 0, stream>>>(d_in[17], dwA2, 2592, flag);
  k_cvt_f32<<<dim3(18), 256, 0, stream>>>(d_in[23], dwF2, 4590, flag);
  k_cvt_f32<<<dim3(36), 256, 0, stream>>>(d_in[7],  prj1, 9216, flag);
  k_cvt_f32<<<dim3(36), 256, 0, stream>>>(d_in[18], prj2, 9216, flag);
  k_cvt_f32<<<dim3(1), 256, 0, stream>>>(d_in[8],  tmp1, 6, flag);
  k_cvt_f32<<<dim3(1), 256, 0, stream>>>(d_in[19], tmp2, 6, flag);
  k_cvt_f32<<<dim3(1), 256, 0, stream>>>(d_in[3],  lnp + 0,   96, flag);
  k_cvt_f32<<<dim3(1), 256, 0, stream>>>(d_in[4],  lnp + 96,  96, flag);
  k_cvt_f32<<<dim3(1), 256, 0, stream>>>(d_in[9],  lnp + 192, 96, flag);
  k_cvt_f32<<<dim3(1), 256, 0, stream>>>(d_in[10], lnp + 288, 96, flag);
  k_cvt_f32<<<dim3(1), 256, 0, stream>>>(d_in[14], lnp + 384, 96, flag);
  k_cvt_f32<<<dim3(1), 256, 0, stream>>>(d_in[15], lnp + 480, 96, flag);
  k_cvt_f32<<<dim3(1), 256, 0, stream>>>(d_in[20], lnp + 576, 96, flag);
  k_cvt_f32<<<dim3(1), 256, 0, stream>>>(d_in[21], lnp + 672, 96, flag);

  // attn: out = res + proj(attn(dw(conv(LN(x)+f))))
  auto attn_stage = [&](const void* x, const u32* xfl, const void* f, const u32* ffl,
                        const float* lw, const float* lb, const u16* Wq,
                        const float* dwf, const float* tmpf, const float* prjf,
                        const void* res, const u32* rfl,
                        void* outx, const u32* ofl) {
    for (int b = 0; b < 2; ++b) {
      const size_t eb = (size_t)b * BELEMS;
      hipMemsetAsync(Sb, 0, 1728 * sizeof(float), stream);
      k_lnp<<<dim3(1024), 256, 0, stream>>>(x, xfl, f, ffl, eb, lw, lb, bufB);
      k_gemm<<<dim3(3, 512), 256, 0, stream>>>(bufB, nullptr, 0, nullptr, nullptr,
                                               nullptr, nullptr,
                                               Wq, 96, 96, 288,
                                               nullptr, nullptr, bufA, nullptr, 0);
      k_dw<<<dim3(16, 288), 256, 0, stream>>>(bufA, dwf, bufB);
      k_reduce_s<<<dim3(128, 6), 256, 0, stream>>>(bufB, Sb, Qn, Kn);
      k_softmax_m<<<dim3(1), 256, 0, stream>>>(Sb, Qn, Kn, tmpf, prjf, Mtb);
      k_gemm<<<dim3(1, 512), 256, 0, stream>>>(bufB + (size_t)192 * NPLANE, nullptr, 0,
                                               nullptr, nullptr, nullptr, nullptr,
                                               Mtb, 96, 96, 96,
                                               res, rfl, outx, ofl, eb);
    }
  };
  auto ffn_stage = [&](const void* x, const u32* xfl,
                       const float* lw, const float* lb, const u16* Wi,
                       const float* dwf, const u16* Wo,
                       void* outx, const u32* ofl) {
    for (int b = 0; b < 2; ++b) {
      const size_t eb = (size_t)b * BELEMS;
      k_lnp<<<dim3(1024), 256, 0, stream>>>(x, xfl, nullptr, nullptr, eb, lw, lb, bufB);
      k_gemm<<<dim3(6, 512), 256, 0, stream>>>(bufB, nullptr, 0, nullptr, nullptr,
                                               nullptr, nullptr,
                                               Wi, 96, 96, 510,
                                               nullptr, nullptr, bufA, nullptr, 0);
      k_dw_gelu<<<dim3(16, 255), 256, 0, stream>>>(bufA, dwf, bufB);
      k_gemm<<<dim3(1, 512), 256, 0, stream>>>(bufB, nullptr, 0,
                                               nullptr, nullptr, nullptr, nullptr,
                                               Wo, 255, 256, 96,
                                               x, xfl, outx, ofl, eb);
    }
  };

  // stage 1: x1 = Fw + attn(LN1(Fw) + F0c)
  attn_stage(Fw, flag, F0c, flag, lnp + 0, lnp + 96, Wq1, dwA1, tmp1, prj1,
             Fw, flag, xcur, nullptr);
  // stage 2: x2 = x1 + ffn(LN2(x1))
  ffn_stage(xcur, nullptr, lnp + 192, lnp + 288, Wi1, dwF1, Wo1, xcur, nullptr);
  // stage 3: x3 = x2 + attn(LN3(x2) + Kd)
  attn_stage(xcur, nullptr, Kdi, flag, lnp + 384, lnp + 480, Wq2, dwA2, tmp2, prj2,
             xcur, nullptr, xcur, nullptr);
  // stage 4: out = x3 + ffn(LN4(x3))
  ffn_stage(xcur, nullptr, lnp + 576, lnp + 672, Wi2, dwF2, Wo2, d_out, flag);
}

// Round 8
// 1051.133 us; speedup vs baseline: 1.7604x; 1.1703x over previous
//
#include <hip/hip_runtime.h>
#include <math.h>

using u16 = unsigned short;
using u32 = unsigned int;
typedef __attribute__((ext_vector_type(8))) short bf16x8;
typedef __attribute__((ext_vector_type(4))) float f32x4;
typedef __attribute__((ext_vector_type(16))) float f32x16;

#define NPLANE 65536
#define BELEMS ((size_t)6291456) /* 96*65536 elements per batch */

__device__ __forceinline__ float bf2f(u16 u) { return __uint_as_float(((u32)u) << 16); }
__device__ __forceinline__ u16 f2bf(float f) {
  if (!__builtin_isfinite(f)) return (u16)0x5F80;  // diagnostic sentinel ~1.8e19
  u32 u = __float_as_uint(f);
  return (u16)((u + 0x7fffu + ((u >> 16) & 1u)) >> 16);
}
__device__ __forceinline__ float4 cvt4(ushort4 v) {
  return make_float4(bf2f(v.x), bf2f(v.y), bf2f(v.z), bf2f(v.w));
}
__device__ __forceinline__ ushort4 pack4(float a, float b, float c, float d) {
  ushort4 o; o.x = f2bf(a); o.y = f2bf(b); o.z = f2bf(c); o.w = f2bf(d); return o;
}

union U16x8 { uint4 u4; bf16x8 v; u16 s[8]; };

// ---------------- dtype detect: ln1_w[0] == 1.0. bf16 -> 0x3F80, fp32 low half -> 0x0000
__global__ void k_detect(const u16* __restrict__ p, u32* __restrict__ flag) {
  if (blockIdx.x == 0 && threadIdx.x == 0) *flag = (p[0] == (u16)0x3F80) ? 0u : 1u;
}

// ---------------- small param convert -> f32
__global__ __launch_bounds__(256) void k_cvt_f32(const void* __restrict__ src,
                                                 float* __restrict__ dst, int n,
                                                 const u32* __restrict__ fl) {
  const int i = blockIdx.x * 256 + threadIdx.x;
  if (i >= n) return;
  dst[i] = (*fl != 0) ? ((const float*)src)[i] : bf2f(((const u16*)src)[i]);
}

// ---------------- weight prep: W[M][Kr] (flagged dtype) -> Wb bf16 [Mpad][Kpad], zero pad
__global__ __launch_bounds__(256) void k_wprep(const void* __restrict__ W, u16* __restrict__ Wb,
                                               int M, int Kr, int Kpad, int total,
                                               const u32* __restrict__ fl) {
  const int idx = blockIdx.x * 256 + threadIdx.x;
  if (idx >= total) return;
  const int m = idx / Kpad, k = idx - m * Kpad;
  u16 v = 0;
  if (m < M && k < Kr) {
    const int si = m * Kr + k;
    v = (*fl != 0) ? f2bf(((const float*)W)[si]) : ((const u16*)W)[si];
  }
  Wb[idx] = v;
}

// ---------------- LN (+optional f add), tiled: 96ch x 64px per block -> plane bf16
__global__ __launch_bounds__(256) void k_lnp(
    const void* __restrict__ x, const u32* __restrict__ xfl,
    const void* __restrict__ f, const u32* __restrict__ ffl,
    size_t eb,
    const float* __restrict__ lnw, const float* __restrict__ lnb,
    u16* __restrict__ out)
{
  __shared__ float xin[96 * 64];
  __shared__ float fin[96 * 64];
  __shared__ float ps[256], pq[256];
  __shared__ float mu[64], rsd[64];
  const int tid = threadIdx.x;
  const int pix0 = blockIdx.x * 64;
  const bool xf = xfl && (*xfl != 0);
  const bool ff = ffl && (*ffl != 0);

#pragma unroll
  for (int i = 0; i < 6; ++i) {
    const int u = tid + i * 256;
    const int c = u >> 4, p4 = (u & 15) << 2;
    const size_t base = eb + (size_t)c * NPLANE + pix0 + p4;
    const float4 v = xf ? *(const float4*)((const float*)x + base)
                        : cvt4(*(const ushort4*)((const u16*)x + base));
    *(float4*)(xin + c * 64 + p4) = v;
    if (f) {
      const float4 fv = ff ? *(const float4*)((const float*)f + base)
                           : cvt4(*(const ushort4*)((const u16*)f + base));
      *(float4*)(fin + c * 64 + p4) = fv;
    }
  }
  __syncthreads();
  {
    const int p = tid & 63, qq = tid >> 6;
    float s = 0.f, q = 0.f;
    const int c0 = qq * 24;
#pragma unroll 8
    for (int c = c0; c < c0 + 24; ++c) {
      const float v = xin[c * 64 + p];
      s += v; q += v * v;
    }
    ps[tid] = s; pq[tid] = q;
  }
  __syncthreads();
  if (tid < 64) {
    const float s = ps[tid] + ps[tid + 64] + ps[tid + 128] + ps[tid + 192];
    const float q = pq[tid] + pq[tid + 64] + pq[tid + 128] + pq[tid + 192];
    const float m = s * (1.f / 96.f);
    mu[tid] = m;
    rsd[tid] = rsqrtf(fmaxf(q * (1.f / 96.f) - m * m, 0.f) + 1e-5f);
  }
  __syncthreads();
#pragma unroll
  for (int i = 0; i < 6; ++i) {
    const int u = tid + i * 256;
    const int c = u >> 4, p4 = (u & 15) << 2;
    const float4 v = *(const float4*)(xin + c * 64 + p4);
    const float w = lnw[c], b = lnb[c];
    float o0 = (v.x - mu[p4 + 0]) * rsd[p4 + 0] * w + b;
    float o1 = (v.y - mu[p4 + 1]) * rsd[p4 + 1] * w + b;
    float o2 = (v.z - mu[p4 + 2]) * rsd[p4 + 2] * w + b;
    float o3 = (v.w - mu[p4 + 3]) * rsd[p4 + 3] * w + b;
    if (f) {
      const float4 fv = *(const float4*)(fin + c * 64 + p4);
      o0 += fv.x; o1 += fv.y; o2 += fv.z; o3 += fv.w;
    }
    *(ushort4*)(out + (size_t)c * NPLANE + pix0 + p4) = pack4(o0, o1, o2, o3);
  }
}

// ---------------- MFMA GEMM: out[oc][n] = sum_k Wb[oc][k] * B[k][n] (+res)
__global__ __launch_bounds__(256) void k_gemm(
    const void* __restrict__ xsrc, const u32* __restrict__ xfl, size_t xeb,
    const void* __restrict__ fsrc, const u32* __restrict__ ffl,
    const float* __restrict__ lnw, const float* __restrict__ lnb,
    const u16* __restrict__ Wb, int K, int Kpad, int OC,
    const void* __restrict__ res, const u32* __restrict__ rfl,
    void* __restrict__ out, const u32* __restrict__ ofl, size_t roeb)
{
  __shared__ uint4 Bt[128 * 16];
  __shared__ float mu[128], rsd[128], ps[256], pq[256];
  const int t = threadIdx.x;
  const int p = t & 127, h = t >> 7;
  const int oc0 = blockIdx.x * 96;
  const int n0 = blockIdx.y * 128;
  const int nglob = n0 + p;
  const int l = t & 63, wid = t >> 6, wm = wid >> 1, wn = wid & 1;
  const bool xf = xfl && (*xfl != 0);
  const bool LN = (lnw != nullptr);

  if (LN) {
    float s = 0.f, q = 0.f;
    const int c0 = h * 48;
    for (int c = c0; c < c0 + 48; ++c) {
      const size_t gi = xeb + (size_t)c * NPLANE + nglob;
      const float v = xf ? ((const float*)xsrc)[gi] : bf2f(((const u16*)xsrc)[gi]);
      s += v; q += v * v;
    }
    ps[t] = s; pq[t] = q;
    __syncthreads();
    if (t < 128) {
      s = ps[t] + ps[t + 128]; q = pq[t] + pq[t + 128];
      const float m = s * (1.f / 96.f);
      mu[t] = m;
      rsd[t] = rsqrtf(fmaxf(q * (1.f / 96.f) - m * m, 0.f) + 1e-5f);
    }
    __syncthreads();
  }

  f32x4 acc[3][4];
#pragma unroll
  for (int m = 0; m < 3; ++m)
#pragma unroll
    for (int n = 0; n < 4; ++n) acc[m][n] = (f32x4){0.f, 0.f, 0.f, 0.f};

  const bool ff = ffl && (*ffl != 0);
  for (int kb = 0; kb < K; kb += 128) {
    if (kb) __syncthreads();
    const int kc = min(128, K - kb);
    const int U = (kc + 7) >> 3;
    const int uh = U >> 1;
    const float lmu = LN ? mu[p] : 0.f, lrs = LN ? rsd[p] : 0.f;
    for (int j = 0; j < uh; ++j) {
      const int u = h * uh + j;
      const int cb = kb + u * 8;
      U16x8 pk;
#pragma unroll
      for (int e = 0; e < 8; ++e) {
        const int c = cb + e;
        u16 r16 = 0;
        if (c < K) {
          const size_t gi = xeb + (size_t)c * NPLANE + nglob;
          if (LN) {
            float v = xf ? ((const float*)xsrc)[gi] : bf2f(((const u16*)xsrc)[gi]);
            v = (v - lmu) * lrs * lnw[c] + lnb[c];
            if (fsrc) {
              v += ff ? ((const float*)fsrc)[gi] : bf2f(((const u16*)fsrc)[gi]);
            }
            r16 = f2bf(v);
          } else {
            r16 = ((const u16*)xsrc)[gi];
          }
        }
        pk.s[e] = r16;
      }
      Bt[p * 16 + (u ^ (p & 7))] = pk.u4;
    }
    __syncthreads();
    const int nks = (kc + 31) >> 5;
    for (int ks = 0; ks < nks; ++ks) {
      U16x8 a[3], b[4];
      const int kk = kb + ks * 32 + ((l >> 4) << 3);
#pragma unroll
      for (int m = 0; m < 3; ++m) {
        const int row = oc0 + wm * 48 + m * 16 + (l & 15);
        a[m].u4 = ((const uint4*)Wb)[((size_t)row * Kpad + kk) >> 3];
      }
#pragma unroll
      for (int ns = 0; ns < 4; ++ns) {
        const int row = wn * 64 + ns * 16 + (l & 15);
        const int up = (ks * 4 + (l >> 4)) ^ (row & 7);
        b[ns].u4 = Bt[row * 16 + up];
      }
#pragma unroll
      for (int m = 0; m < 3; ++m)
#pragma unroll
        for (int ns = 0; ns < 4; ++ns)
          acc[m][ns] = __builtin_amdgcn_mfma_f32_16x16x32_bf16(a[m].v, b[ns].v, acc[m][ns], 0, 0, 0);
    }
  }

  const bool rf = rfl && (*rfl != 0);
  const bool of = ofl && (*ofl != 0);
#pragma unroll
  for (int m = 0; m < 3; ++m) {
    const int ocb = oc0 + wm * 48 + m * 16 + ((l >> 4) << 2);
#pragma unroll
    for (int ns = 0; ns < 4; ++ns) {
      const int n = n0 + wn * 64 + ns * 16 + (l & 15);
#pragma unroll
      for (int r = 0; r < 4; ++r) {
        const int oc = ocb + r;
        if (oc < OC) {
          float v = acc[m][ns][r];
          const size_t gi = roeb + (size_t)oc * NPLANE + n;
          if (res) v += rf ? ((const float*)res)[gi] : bf2f(((const u16*)res)[gi]);
          if (of) ((float*)out)[gi] = v;
          else    ((u16*)out)[gi] = f2bf(v);
        }
      }
    }
  }
}

// ---------------- depthwise 3x3 (zero pad 1). grid (16 rowtiles, CH), block 256
__global__ __launch_bounds__(256) void k_dw(
    const u16* __restrict__ in, const float* __restrict__ w9, u16* __restrict__ out)
{
  const int c = blockIdx.y;
  const int r0 = blockIdx.x * 16;
  __shared__ float tt[18 * 256];
  const int tid = threadIdx.x;
  const u16* ip = in + (size_t)c * NPLANE;
  for (int u = tid; u < 1152; u += 256) {
    const int r = u >> 6, p4 = (u & 63) << 2;
    const int gr = r0 - 1 + r;
    float4 fv = make_float4(0.f, 0.f, 0.f, 0.f);
    if (gr >= 0 && gr < 256) fv = cvt4(*(const ushort4*)(ip + gr * 256 + p4));
    *(float4*)(tt + r * 256 + p4) = fv;
  }
  float wr[9];
#pragma unroll
  for (int i = 0; i < 9; ++i) wr[i] = w9[c * 9 + i];
  __syncthreads();
  const int col = tid;
  const bool cm = col > 0, cp = col < 255;
  float a0 = cm ? tt[col - 1] : 0.f, a1 = tt[col], a2 = cp ? tt[col + 1] : 0.f;
  float b0 = cm ? tt[256 + col - 1] : 0.f, b1 = tt[256 + col], b2 = cp ? tt[256 + col + 1] : 0.f;
  u16* op = out + (size_t)c * NPLANE + (size_t)r0 * 256 + col;
#pragma unroll
  for (int rr = 0; rr < 16; ++rr) {
    const int rn = (rr + 2) * 256;
    const float c1 = tt[rn + col];
    const float c0 = cm ? tt[rn + col - 1] : 0.f;
    const float c2 = cp ? tt[rn + col + 1] : 0.f;
    const float s = wr[0] * a0 + wr[1] * a1 + wr[2] * a2
                  + wr[3] * b0 + wr[4] * b1 + wr[5] * b2
                  + wr[6] * c0 + wr[7] * c1 + wr[8] * c2;
    op[rr * 256] = f2bf(s);
    a0 = b0; a1 = b1; a2 = b2; b0 = c0; b1 = c1; b2 = c2;
  }
}

// ---------------- depthwise 3x3 pair + gelu(x1)*x2. in: 510 planes, out: 255 planes
__global__ __launch_bounds__(256) void k_dw_gelu(
    const u16* __restrict__ in, const float* __restrict__ w9, u16* __restrict__ out)
{
  const int c = blockIdx.y;
  const int r0 = blockIdx.x * 16;
  __shared__ float t1[18 * 256];
  __shared__ float t2[18 * 256];
  const int tid = threadIdx.x;
  const u16* ip1 = in + (size_t)c * NPLANE;
  const u16* ip2 = in + (size_t)(c + 255) * NPLANE;
  for (int u = tid; u < 1152; u += 256) {
    const int r = u >> 6, p4 = (u & 63) << 2;
    const int gr = r0 - 1 + r;
    float4 fa = make_float4(0.f, 0.f, 0.f, 0.f), fb = fa;
    if (gr >= 0 && gr < 256) {
      fa = cvt4(*(const ushort4*)(ip1 + gr * 256 + p4));
      fb = cvt4(*(const ushort4*)(ip2 + gr * 256 + p4));
    }
    *(float4*)(t1 + r * 256 + p4) = fa;
    *(float4*)(t2 + r * 256 + p4) = fb;
  }
  float wa[9], wb[9];
#pragma unroll
  for (int i = 0; i < 9; ++i) { wa[i] = w9[c * 9 + i]; wb[i] = w9[(c + 255) * 9 + i]; }
  __syncthreads();
  const int col = tid;
  const bool cm = col > 0, cp = col < 255;
  float a0 = cm ? t1[col - 1] : 0.f, a1 = t1[col], a2 = cp ? t1[col + 1] : 0.f;
  float b0 = cm ? t1[256 + col - 1] : 0.f, b1 = t1[256 + col], b2 = cp ? t1[256 + col + 1] : 0.f;
  float d0 = cm ? t2[col - 1] : 0.f, d1 = t2[col], d2 = cp ? t2[col + 1] : 0.f;
  float e0 = cm ? t2[256 + col - 1] : 0.f, e1 = t2[256 + col], e2 = cp ? t2[256 + col + 1] : 0.f;
  u16* op = out + (size_t)c * NPLANE + (size_t)r0 * 256 + col;
#pragma unroll
  for (int rr = 0; rr < 16; ++rr) {
    const int rn = (rr + 2) * 256;
    const float c1 = t1[rn + col];
    const float c0 = cm ? t1[rn + col - 1] : 0.f;
    const float c2 = cp ? t1[rn + col + 1] : 0.f;
    const float g1 = wa[0] * a0 + wa[1] * a1 + wa[2] * a2
                   + wa[3] * b0 + wa[4] * b1 + wa[5] * b2
                   + wa[6] * c0 + wa[7] * c1 + wa[8] * c2;
    const float f1 = t2[rn + col];
    const float f0 = cm ? t2[rn + col - 1] : 0.f;
    const float f2 = cp ? t2[rn + col + 1] : 0.f;
    const float g2 = wb[0] * d0 + wb[1] * d1 + wb[2] * d2
                   + wb[3] * e0 + wb[4] * e1 + wb[5] * e2
                   + wb[6] * f0 + wb[7] * f1 + wb[8] * f2;
    const float gel = 0.5f * g1 * (1.f + erff(g1 * 0.70710678118654752f));
    op[rr * 256] = f2bf(gel * g2);
    a0 = b0; a1 = b1; a2 = b2; b0 = c0; b1 = c1; b2 = c2;
    d0 = e0; d1 = e1; d2 = e2; e0 = f0; e1 = f1; e2 = f2;
  }
}

// ---------------- MFMA Gram: G = [q;k]·[q;k]^T per head/chunk -> S quadrant + norms
// qkv: q planes 0-95, k planes 96-191. grid (128 chunks of 512px, 6 heads), block 256.
__global__ __launch_bounds__(256) void k_reduce_s(
    const u16* __restrict__ qkv, float* __restrict__ S,
    float* __restrict__ qn2, float* __restrict__ kn2)
{
  const int h = blockIdx.y;
  const int n0 = blockIdx.x * 512;
  __shared__ uint4 st[64 * 33];  // [pxchunk16B c][row r] 16B units, 33792 B
  const int tid = threadIdx.x;
  const int l = tid & 63, w = tid >> 6;

  // stage 32 rows (16 q + 16 k) x 512 px, coalesced 16B loads
#pragma unroll
  for (int i = 0; i < 8; ++i) {
    const int idx = tid + i * 256;
    const int c = idx & 63, r = idx >> 6;
    const int plane = (r < 16) ? (h * 16 + r) : (96 + h * 16 + (r - 16));
    st[c * 33 + r] = *(const uint4*)(qkv + (size_t)plane * NPLANE + n0 + c * 8);
  }
  __syncthreads();

  // wave w handles px [w*128, (w+1)*128): 8 MFMA steps of K=16
  f32x16 acc;
#pragma unroll
  for (int j = 0; j < 16; ++j) acc[j] = 0.f;
  const int row = l & 31;
  const int cg = (w << 4) + (l >> 5);  // chunk base for this lane's K-group
#pragma unroll
  for (int s = 0; s < 8; ++s) {
    U16x8 frag;
    frag.u4 = st[(cg + s * 2) * 33 + row];
    acc = __builtin_amdgcn_mfma_f32_32x32x16_bf16(frag.v, frag.v, acc, 0, 0, 0);
  }
  __syncthreads();

  // cross-wave partial reduce in LDS (reuse st), then atomics
  float* fs = (float*)st;
#pragma unroll
  for (int j = 0; j < 16; ++j) {
    const int rj = (j & 3) + 8 * (j >> 2) + 4 * (l >> 5);
    fs[w * 1024 + rj * 32 + (l & 31)] = acc[j];
  }
  __syncthreads();
#pragma unroll
  for (int e4 = 0; e4 < 4; ++e4) {
    const int e = tid * 4 + e4;
    const float v = fs[e] + fs[1024 + e] + fs[2048 + e] + fs[3072 + e];
    const int r = e >> 5, cc = e & 31;
    if (r < 16 && cc >= 16) atomicAdd(S + h * 256 + r * 16 + (cc - 16), v);
    if (r == cc) {
      if (r < 16) atomicAdd(qn2 + h * 16 + r, v);
      else        atomicAdd(kn2 + h * 16 + (r - 16), v);
    }
  }
}

// ---------------- softmax + fold proj -> Mtb bf16 [e][dg] (96x96)
__global__ __launch_bounds__(256) void k_softmax_m(
    const float* __restrict__ S, const float* __restrict__ qn2, const float* __restrict__ kn2,
    const float* __restrict__ temp, const float* __restrict__ proj, u16* __restrict__ Mtb)
{
  __shared__ float attn[6 * 256];
  const int tid = threadIdx.x;
  if (tid < 96) {
    const int h = tid >> 4, i = tid & 15;
    const float qn = fmaxf(sqrtf(qn2[tid]), 1e-12f);
    const float tp = temp[h];
    float row[16];
    float mx = -3.4e38f;
#pragma unroll
    for (int d = 0; d < 16; ++d) {
      const float kn = fmaxf(sqrtf(kn2[h * 16 + d]), 1e-12f);
      row[d] = S[h * 256 + i * 16 + d] / (qn * kn) * tp;
      mx = fmaxf(mx, row[d]);
    }
    float sum = 0.f;
#pragma unroll
    for (int d = 0; d < 16; ++d) { row[d] = expf(row[d] - mx); sum += row[d]; }
    const float inv = 1.f / sum;
#pragma unroll
    for (int d = 0; d < 16; ++d) attn[h * 256 + i * 16 + d] = row[d] * inv;
  }
  __syncthreads();
  for (int u = tid; u < 9216; u += 256) {
    const int e = u / 96, dg = u - e * 96;
    const int h = dg >> 4, d = dg & 15;
    float s = 0.f;
#pragma unroll
    for (int i = 0; i < 16; ++i)
      s += proj[e * 96 + h * 16 + i] * attn[h * 256 + i * 16 + d];
    Mtb[u] = f2bf(s);
  }
}

extern "C" void kernel_launch(void* const* d_in, const int* in_sizes, int n_in,
                              void* d_out, int out_size, void* d_ws, size_t ws_size,
                              hipStream_t stream)
{
  (void)in_sizes; (void)n_in; (void)out_size;
  if (ws_size < (size_t)130400000) return;

  const void* Fw  = d_in[0];
  const void* F0c = d_in[1];
  const void* Kdi = d_in[2];

  char* ws = (char*)d_ws;
  u16* xcur = (u16*)ws;
  u16* bufA = (u16*)(ws + 25165824);
  u16* bufB = (u16*)(ws + 92012544);
  u16* wb   = (u16*)(ws + 129761280);
  u16* Wq1 = wb;           u16* Wi1 = wb + 27648;   u16* Wo1 = wb + 82944;
  u16* Wq2 = wb + 107520;  u16* Wi2 = wb + 135168;  u16* Wo2 = wb + 190464;
  u16* Mtb = wb + 215040;  // 96x96
  float* fz = (float*)(ws + 130209792);
  float* dwA1 = fz;          float* dwF1 = fz + 2592;
  float* dwA2 = fz + 7182;   float* dwF2 = fz + 9774;
  float* prj1 = fz + 14364;  float* prj2 = fz + 23580;
  float* tmp1 = fz + 32796;  float* tmp2 = fz + 32802;
  float* lnp  = fz + 32808;  // 8 x 96
  float* Sb   = fz + 33576;  float* Qn = fz + 35112;  float* Kn = fz + 35208;
  u32*  flag  = (u32*)(fz + 35304);

  k_detect<<<1, 64, 0, stream>>>((const u16*)d_in[3], flag);

  k_wprep<<<dim3(108), 256, 0, stream>>>(d_in[5],  Wq1, 288, 96, 96,  27648, flag);
  k_wprep<<<dim3(216), 256, 0, stream>>>(d_in[11], Wi1, 510, 96, 96,  55296, flag);
  k_wprep<<<dim3(96),  256, 0, stream>>>(d_in[13], Wo1, 96,  255, 256, 24576, flag);
  k_wprep<<<dim3(108), 256, 0, stream>>>(d_in[16], Wq2, 288, 96, 96,  27648, flag);
  k_wprep<<<dim3(216), 256, 0, stream>>>(d_in[22], Wi2, 510, 96, 96,  55296, flag);
  k_wprep<<<dim3(96),  256, 0, stream>>>(d_in[24], Wo2, 96,  255, 256, 24576, flag);

  k_cvt_f32<<<dim3(11), 256, 0, stream>>>(d_in[6],  dwA1, 2592, flag);
  k_cvt_f32<<<dim3(18), 256, 0, stream>>>(d_in[12], dwF1, 4590, flag);
  k_cvt_f32<<<dim3(11), 256, 0, stream>>>(d_in[17], dwA2, 2592, flag);
  k_cvt_f32<<<dim3(18), 256, 0, stream>>>(d_in[23], dwF2, 4590, flag);
  k_cvt_f32<<<dim3(36), 256, 0, stream>>>(d_in[7],  prj1, 9216, flag);
  k_cvt_f32<<<dim3(36), 256, 0, stream>>>(d_in[18], prj2, 9216, flag);
  k_cvt_f32<<<dim3(1), 256, 0, stream>>>(d_in[8],  tmp1, 6, flag);
  k_cvt_f32<<<dim3(1), 256, 0, stream>>>(d_in[19], tmp2, 6, flag);
  k_cvt_f32<<<dim3(1), 256, 0, stream>>>(d_in[3],  lnp + 0,   96, flag);
  k_cvt_f32<<<dim3(1), 256, 0, stream>>>(d_in[4],  lnp + 96,  96, flag);
  k_cvt_f32<<<dim3(1), 256, 0, stream>>>(d_in[9],  lnp + 192, 96, flag);
  k_cvt_f32<<<dim3(1), 256, 0, stream>>>(d_in[10], lnp + 288, 96, flag);
  k_cvt_f32<<<dim3(1), 256, 0, stream>>>(d_in[14], lnp + 384, 96, flag);
  k_cvt_f32<<<dim3(1), 256, 0, stream>>>(d_in[15], lnp + 480, 96, flag);
  k_cvt_f32<<<dim3(1), 256, 0, stream>>>(d_in[20], lnp + 576, 96, flag);
  k_cvt_f32<<<dim3(1), 256, 0, stream>>>(d_in[21], lnp + 672, 96, flag);

  // attn: out = res + proj(attn(dw(conv(LN(x)+f))))
  auto attn_stage = [&](const void* x, const u32* xfl, const void* f, const u32* ffl,
                        const float* lw, const float* lb, const u16* Wq,
                        const float* dwf, const float* tmpf, const float* prjf,
                        const void* res, const u32* rfl,
                        void* outx, const u32* ofl) {
    for (int b = 0; b < 2; ++b) {
      const size_t eb = (size_t)b * BELEMS;
      hipMemsetAsync(Sb, 0, 1728 * sizeof(float), stream);
      k_lnp<<<dim3(1024), 256, 0, stream>>>(x, xfl, f, ffl, eb, lw, lb, bufB);
      k_gemm<<<dim3(3, 512), 256, 0, stream>>>(bufB, nullptr, 0, nullptr, nullptr,
                                               nullptr, nullptr,
                                               Wq, 96, 96, 288,
                                               nullptr, nullptr, bufA, nullptr, 0);
      k_dw<<<dim3(16, 288), 256, 0, stream>>>(bufA, dwf, bufB);
      k_reduce_s<<<dim3(128, 6), 256, 0, stream>>>(bufB, Sb, Qn, Kn);
      k_softmax_m<<<dim3(1), 256, 0, stream>>>(Sb, Qn, Kn, tmpf, prjf, Mtb);
      k_gemm<<<dim3(1, 512), 256, 0, stream>>>(bufB + (size_t)192 * NPLANE, nullptr, 0,
                                               nullptr, nullptr, nullptr, nullptr,
                                               Mtb, 96, 96, 96,
                                               res, rfl, outx, ofl, eb);
    }
  };
  auto ffn_stage = [&](const void* x, const u32* xfl,
                       const float* lw, const float* lb, const u16* Wi,
                       const float* dwf, const u16* Wo,
                       void* outx, const u32* ofl) {
    for (int b = 0; b < 2; ++b) {
      const size_t eb = (size_t)b * BELEMS;
      k_lnp<<<dim3(1024), 256, 0, stream>>>(x, xfl, nullptr, nullptr, eb, lw, lb, bufB);
      k_gemm<<<dim3(6, 512), 256, 0, stream>>>(bufB, nullptr, 0, nullptr, nullptr,
                                               nullptr, nullptr,
                                               Wi, 96, 96, 510,
                                               nullptr, nullptr, bufA, nullptr, 0);
      k_dw_gelu<<<dim3(16, 255), 256, 0, stream>>>(bufA, dwf, bufB);
      k_gemm<<<dim3(1, 512), 256, 0, stream>>>(bufB, nullptr, 0,
                                               nullptr, nullptr, nullptr, nullptr,
                                               Wo, 255, 256, 96,
                                               x, xfl, outx, ofl, eb);
    }
  };

  // stage 1: x1 = Fw + attn(LN1(Fw) + F0c)
  attn_stage(Fw, flag, F0c, flag, lnp + 0, lnp + 96, Wq1, dwA1, tmp1, prj1,
             Fw, flag, xcur, nullptr);
  // stage 2: x2 = x1 + ffn(LN2(x1))
  ffn_stage(xcur, nullptr, lnp + 192, lnp + 288, Wi1, dwF1, Wo1, xcur, nullptr);
  // stage 3: x3 = x2 + attn(LN3(x2) + Kd)
  attn_stage(xcur, nullptr, Kdi, flag, lnp + 384, lnp + 480, Wq2, dwA2, tmp2, prj2,
             xcur, nullptr, xcur, nullptr);
  // stage 4: out = x3 + ffn(LN4(x3))
  ffn_stage(xcur, nullptr, lnp + 576, lnp + 672, Wi2, dwF2, Wo2, d_out, flag);
}

// Round 9
// 989.094 us; speedup vs baseline: 1.8708x; 1.0627x over previous
//
#include <hip/hip_runtime.h>
#include <math.h>

using u16 = unsigned short;
using u32 = unsigned int;
typedef __attribute__((ext_vector_type(8))) short bf16x8;
typedef __attribute__((ext_vector_type(4))) float f32x4;
typedef __attribute__((ext_vector_type(16))) float f32x16;

#define NPLANE 65536
#define BELEMS ((size_t)6291456) /* 96*65536 elements per batch */

__device__ __forceinline__ float bf2f(u16 u) { return __uint_as_float(((u32)u) << 16); }
__device__ __forceinline__ u16 f2bf(float f) {
  if (!__builtin_isfinite(f)) return (u16)0x5F80;  // diagnostic sentinel ~1.8e19
  u32 u = __float_as_uint(f);
  return (u16)((u + 0x7fffu + ((u >> 16) & 1u)) >> 16);
}
__device__ __forceinline__ float4 cvt4(ushort4 v) {
  return make_float4(bf2f(v.x), bf2f(v.y), bf2f(v.z), bf2f(v.w));
}
__device__ __forceinline__ ushort4 pack4(float a, float b, float c, float d) {
  ushort4 o; o.x = f2bf(a); o.y = f2bf(b); o.z = f2bf(c); o.w = f2bf(d); return o;
}

union U16x8 { uint4 u4; bf16x8 v; u16 s[8]; };

// ---------------- dtype detect: ln1_w[0] == 1.0. bf16 -> 0x3F80, fp32 low half -> 0x0000
__global__ void k_detect(const u16* __restrict__ p, u32* __restrict__ flag) {
  if (blockIdx.x == 0 && threadIdx.x == 0) *flag = (p[0] == (u16)0x3F80) ? 0u : 1u;
}

// ---------------- small param convert -> f32
__global__ __launch_bounds__(256) void k_cvt_f32(const void* __restrict__ src,
                                                 float* __restrict__ dst, int n,
                                                 const u32* __restrict__ fl) {
  const int i = blockIdx.x * 256 + threadIdx.x;
  if (i >= n) return;
  dst[i] = (*fl != 0) ? ((const float*)src)[i] : bf2f(((const u16*)src)[i]);
}

// ---------------- weight prep: W[M][Kr] (flagged dtype) -> Wb bf16 [Mpad][Kpad], zero pad
__global__ __launch_bounds__(256) void k_wprep(const void* __restrict__ W, u16* __restrict__ Wb,
                                               int M, int Kr, int Kpad, int total,
                                               const u32* __restrict__ fl) {
  const int idx = blockIdx.x * 256 + threadIdx.x;
  if (idx >= total) return;
  const int m = idx / Kpad, k = idx - m * Kpad;
  u16 v = 0;
  if (m < M && k < Kr) {
    const int si = m * Kr + k;
    v = (*fl != 0) ? f2bf(((const float*)W)[si]) : ((const u16*)W)[si];
  }
  Wb[idx] = v;
}

// ---------------- LN (+optional f add), tiled 96ch x 64px -> TRANSPOSED xT [NPLANE][96] bf16
__global__ __launch_bounds__(256) void k_lnp(
    const void* __restrict__ x, const u32* __restrict__ xfl,
    const void* __restrict__ f, const u32* __restrict__ ffl,
    size_t eb,
    const float* __restrict__ lnw, const float* __restrict__ lnb,
    u16* __restrict__ xT)
{
  __shared__ float xin[96 * 64];
  __shared__ float fin[96 * 64];
  __shared__ float ps[256], pq[256];
  __shared__ float mu[64], rsd[64];
  const int tid = threadIdx.x;
  const int pix0 = blockIdx.x * 64;
  const bool xf = xfl && (*xfl != 0);
  const bool ff = ffl && (*ffl != 0);

#pragma unroll
  for (int i = 0; i < 6; ++i) {
    const int u = tid + i * 256;
    const int c = u >> 4, p4 = (u & 15) << 2;
    const size_t base = eb + (size_t)c * NPLANE + pix0 + p4;
    const float4 v = xf ? *(const float4*)((const float*)x + base)
                        : cvt4(*(const ushort4*)((const u16*)x + base));
    *(float4*)(xin + c * 64 + p4) = v;
    if (f) {
      const float4 fv = ff ? *(const float4*)((const float*)f + base)
                           : cvt4(*(const ushort4*)((const u16*)f + base));
      *(float4*)(fin + c * 64 + p4) = fv;
    }
  }
  __syncthreads();
  {
    const int p = tid & 63, qq = tid >> 6;
    float s = 0.f, q = 0.f;
    const int c0 = qq * 24;
#pragma unroll 8
    for (int c = c0; c < c0 + 24; ++c) {
      const float v = xin[c * 64 + p];
      s += v; q += v * v;
    }
    ps[tid] = s; pq[tid] = q;
  }
  __syncthreads();
  if (tid < 64) {
    const float s = ps[tid] + ps[tid + 64] + ps[tid + 128] + ps[tid + 192];
    const float q = pq[tid] + pq[tid + 64] + pq[tid + 128] + pq[tid + 192];
    const float m = s * (1.f / 96.f);
    mu[tid] = m;
    rsd[tid] = rsqrtf(fmaxf(q * (1.f / 96.f) - m * m, 0.f) + 1e-5f);
  }
  __syncthreads();
  // apply LN (+f) in place in LDS
#pragma unroll
  for (int i = 0; i < 6; ++i) {
    const int u = tid + i * 256;
    const int c = u >> 4, p4 = (u & 15) << 2;
    const float4 v = *(const float4*)(xin + c * 64 + p4);
    const float w = lnw[c], b = lnb[c];
    float o0 = (v.x - mu[p4 + 0]) * rsd[p4 + 0] * w + b;
    float o1 = (v.y - mu[p4 + 1]) * rsd[p4 + 1] * w + b;
    float o2 = (v.z - mu[p4 + 2]) * rsd[p4 + 2] * w + b;
    float o3 = (v.w - mu[p4 + 3]) * rsd[p4 + 3] * w + b;
    if (f) {
      const float4 fv = *(const float4*)(fin + c * 64 + p4);
      o0 += fv.x; o1 += fv.y; o2 += fv.z; o3 += fv.w;
    }
    *(float4*)(xin + c * 64 + p4) = make_float4(o0, o1, o2, o3);
  }
  __syncthreads();
  // transposed store: row n = 96 ch contiguous; 768 uint4 units, coalesced
#pragma unroll
  for (int i = 0; i < 3; ++i) {
    const int u = tid + i * 256;
    const int px = u / 12, q = u - px * 12;
    U16x8 pk;
#pragma unroll
    for (int e = 0; e < 8; ++e) pk.s[e] = f2bf(xin[(q * 8 + e) * 64 + px]);
    *(uint4*)(xT + (size_t)(pix0 + px) * 96 + q * 8) = pk.u4;
  }
}

// ---------------- MFMA GEMM (BT input, K=96): out[oc][n] = sum_k Wb[oc][k]*BT[n][k]
// BT: [NPLANE][96] bf16 rows contiguous. Block 256 (4 waves 2x2), tile 96oc x 128px.
// grid (ceil(OC/96), NPLANE/128). Wb: [Mpad][96].
__global__ __launch_bounds__(256) void k_gemm_bt(
    const u16* __restrict__ BT, const u16* __restrict__ Wb, int OC,
    u16* __restrict__ out)
{
  constexpr int LP = 104;  // padded row stride in u16 (2-way free bank aliasing)
  __shared__ u16 Bs[128 * LP];
  const int t = threadIdx.x;
  const int oc0 = blockIdx.x * 96;
  const int n0 = blockIdx.y * 128;
  const int l = t & 63, wid = t >> 6, wm = wid >> 1, wn = wid & 1;

  // stage 128 rows x 96 u16 = contiguous 24.5 KB, 6 x uint4 per thread
  const uint4* src = (const uint4*)(BT + (size_t)n0 * 96);
#pragma unroll
  for (int i = 0; i < 6; ++i) {
    const int u = t + i * 256;
    const int r = u / 12, q = u - r * 12;
    *(uint4*)(Bs + r * LP + q * 8) = src[u];
  }
  __syncthreads();

  f32x4 acc[3][4];
#pragma unroll
  for (int m = 0; m < 3; ++m)
#pragma unroll
    for (int n = 0; n < 4; ++n) acc[m][n] = (f32x4){0.f, 0.f, 0.f, 0.f};

#pragma unroll
  for (int ks = 0; ks < 3; ++ks) {
    const int kk = (ks << 5) + ((l >> 4) << 3);
    U16x8 a[3], b[4];
#pragma unroll
    for (int m = 0; m < 3; ++m)
      a[m].u4 = *(const uint4*)(Wb + (size_t)(oc0 + wm * 48 + m * 16 + (l & 15)) * 96 + kk);
#pragma unroll
    for (int ns = 0; ns < 4; ++ns)
      b[ns].u4 = *(const uint4*)(Bs + (wn * 64 + ns * 16 + (l & 15)) * LP + kk);
#pragma unroll
    for (int m = 0; m < 3; ++m)
#pragma unroll
      for (int ns = 0; ns < 4; ++ns)
        acc[m][ns] = __builtin_amdgcn_mfma_f32_16x16x32_bf16(a[m].v, b[ns].v, acc[m][ns], 0, 0, 0);
  }

#pragma unroll
  for (int m = 0; m < 3; ++m) {
    const int ocb = oc0 + wm * 48 + m * 16 + ((l >> 4) << 2);
#pragma unroll
    for (int ns = 0; ns < 4; ++ns) {
      const int n = n0 + wn * 64 + ns * 16 + (l & 15);
#pragma unroll
      for (int r = 0; r < 4; ++r) {
        const int oc = ocb + r;
        if (oc < OC) out[(size_t)oc * NPLANE + n] = f2bf(acc[m][ns][r]);
      }
    }
  }
}

// ---------------- MFMA GEMM (plane input): out[oc][n] = sum_k Wb[oc][k] * B[k][n] (+res)
__global__ __launch_bounds__(256) void k_gemm(
    const void* __restrict__ xsrc, const u32* __restrict__ xfl, size_t xeb,
    const void* __restrict__ fsrc, const u32* __restrict__ ffl,
    const float* __restrict__ lnw, const float* __restrict__ lnb,
    const u16* __restrict__ Wb, int K, int Kpad, int OC,
    const void* __restrict__ res, const u32* __restrict__ rfl,
    void* __restrict__ out, const u32* __restrict__ ofl, size_t roeb)
{
  __shared__ uint4 Bt[128 * 16];
  const int t = threadIdx.x;
  const int p = t & 127, h = t >> 7;
  const int oc0 = blockIdx.x * 96;
  const int n0 = blockIdx.y * 128;
  const int nglob = n0 + p;
  const int l = t & 63, wid = t >> 6, wm = wid >> 1, wn = wid & 1;
  (void)xfl; (void)fsrc; (void)ffl; (void)lnw; (void)lnb;

  f32x4 acc[3][4];
#pragma unroll
  for (int m = 0; m < 3; ++m)
#pragma unroll
    for (int n = 0; n < 4; ++n) acc[m][n] = (f32x4){0.f, 0.f, 0.f, 0.f};

  for (int kb = 0; kb < K; kb += 128) {
    if (kb) __syncthreads();
    const int kc = min(128, K - kb);
    const int U = (kc + 7) >> 3;
    const int uh = U >> 1;
    for (int j = 0; j < uh; ++j) {
      const int u = h * uh + j;
      const int cb = kb + u * 8;
      U16x8 pk;
#pragma unroll
      for (int e = 0; e < 8; ++e) {
        const int c = cb + e;
        pk.s[e] = (c < K) ? ((const u16*)xsrc)[xeb + (size_t)c * NPLANE + nglob] : (u16)0;
      }
      Bt[p * 16 + (u ^ (p & 7))] = pk.u4;
    }
    __syncthreads();
    const int nks = (kc + 31) >> 5;
    for (int ks = 0; ks < nks; ++ks) {
      U16x8 a[3], b[4];
      const int kk = kb + ks * 32 + ((l >> 4) << 3);
#pragma unroll
      for (int m = 0; m < 3; ++m) {
        const int row = oc0 + wm * 48 + m * 16 + (l & 15);
        a[m].u4 = ((const uint4*)Wb)[((size_t)row * Kpad + kk) >> 3];
      }
#pragma unroll
      for (int ns = 0; ns < 4; ++ns) {
        const int row = wn * 64 + ns * 16 + (l & 15);
        const int up = (ks * 4 + (l >> 4)) ^ (row & 7);
        b[ns].u4 = Bt[row * 16 + up];
      }
#pragma unroll
      for (int m = 0; m < 3; ++m)
#pragma unroll
        for (int ns = 0; ns < 4; ++ns)
          acc[m][ns] = __builtin_amdgcn_mfma_f32_16x16x32_bf16(a[m].v, b[ns].v, acc[m][ns], 0, 0, 0);
    }
  }

  const bool rf = rfl && (*rfl != 0);
  const bool of = ofl && (*ofl != 0);
#pragma unroll
  for (int m = 0; m < 3; ++m) {
    const int ocb = oc0 + wm * 48 + m * 16 + ((l >> 4) << 2);
#pragma unroll
    for (int ns = 0; ns < 4; ++ns) {
      const int n = n0 + wn * 64 + ns * 16 + (l & 15);
#pragma unroll
      for (int r = 0; r < 4; ++r) {
        const int oc = ocb + r;
        if (oc < OC) {
          float v = acc[m][ns][r];
          const size_t gi = roeb + (size_t)oc * NPLANE + n;
          if (res) v += rf ? ((const float*)res)[gi] : bf2f(((const u16*)res)[gi]);
          if (of) ((float*)out)[gi] = v;
          else    ((u16*)out)[gi] = f2bf(v);
        }
      }
    }
  }
}

// ---------------- depthwise 3x3 (zero pad 1). grid (16 rowtiles, CH), block 256
__global__ __launch_bounds__(256) void k_dw(
    const u16* __restrict__ in, const float* __restrict__ w9, u16* __restrict__ out)
{
  const int c = blockIdx.y;
  const int r0 = blockIdx.x * 16;
  __shared__ float tt[18 * 256];
  const int tid = threadIdx.x;
  const u16* ip = in + (size_t)c * NPLANE;
  for (int u = tid; u < 1152; u += 256) {
    const int r = u >> 6, p4 = (u & 63) << 2;
    const int gr = r0 - 1 + r;
    float4 fv = make_float4(0.f, 0.f, 0.f, 0.f);
    if (gr >= 0 && gr < 256) fv = cvt4(*(const ushort4*)(ip + gr * 256 + p4));
    *(float4*)(tt + r * 256 + p4) = fv;
  }
  float wr[9];
#pragma unroll
  for (int i = 0; i < 9; ++i) wr[i] = w9[c * 9 + i];
  __syncthreads();
  const int col = tid;
  const bool cm = col > 0, cp = col < 255;
  float a0 = cm ? tt[col - 1] : 0.f, a1 = tt[col], a2 = cp ? tt[col + 1] : 0.f;
  float b0 = cm ? tt[256 + col - 1] : 0.f, b1 = tt[256 + col], b2 = cp ? tt[256 + col + 1] : 0.f;
  u16* op = out + (size_t)c * NPLANE + (size_t)r0 * 256 + col;
#pragma unroll
  for (int rr = 0; rr < 16; ++rr) {
    const int rn = (rr + 2) * 256;
    const float c1 = tt[rn + col];
    const float c0 = cm ? tt[rn + col - 1] : 0.f;
    const float c2 = cp ? tt[rn + col + 1] : 0.f;
    const float s = wr[0] * a0 + wr[1] * a1 + wr[2] * a2
                  + wr[3] * b0 + wr[4] * b1 + wr[5] * b2
                  + wr[6] * c0 + wr[7] * c1 + wr[8] * c2;
    op[rr * 256] = f2bf(s);
    a0 = b0; a1 = b1; a2 = b2; b0 = c0; b1 = c1; b2 = c2;
  }
}

// ---------------- depthwise 3x3 pair + gelu(x1)*x2. in: 510 planes, out: 255 planes
__global__ __launch_bounds__(256) void k_dw_gelu(
    const u16* __restrict__ in, const float* __restrict__ w9, u16* __restrict__ out)
{
  const int c = blockIdx.y;
  const int r0 = blockIdx.x * 16;
  __shared__ float t1[18 * 256];
  __shared__ float t2[18 * 256];
  const int tid = threadIdx.x;
  const u16* ip1 = in + (size_t)c * NPLANE;
  const u16* ip2 = in + (size_t)(c + 255) * NPLANE;
  for (int u = tid; u < 1152; u += 256) {
    const int r = u >> 6, p4 = (u & 63) << 2;
    const int gr = r0 - 1 + r;
    float4 fa = make_float4(0.f, 0.f, 0.f, 0.f), fb = fa;
    if (gr >= 0 && gr < 256) {
      fa = cvt4(*(const ushort4*)(ip1 + gr * 256 + p4));
      fb = cvt4(*(const ushort4*)(ip2 + gr * 256 + p4));
    }
    *(float4*)(t1 + r * 256 + p4) = fa;
    *(float4*)(t2 + r * 256 + p4) = fb;
  }
  float wa[9], wb[9];
#pragma unroll
  for (int i = 0; i < 9; ++i) { wa[i] = w9[c * 9 + i]; wb[i] = w9[(c + 255) * 9 + i]; }
  __syncthreads();
  const int col = tid;
  const bool cm = col > 0, cp = col < 255;
  float a0 = cm ? t1[col - 1] : 0.f, a1 = t1[col], a2 = cp ? t1[col + 1] : 0.f;
  float b0 = cm ? t1[256 + col - 1] : 0.f, b1 = t1[256 + col], b2 = cp ? t1[256 + col + 1] : 0.f;
  float d0 = cm ? t2[col - 1] : 0.f, d1 = t2[col], d2 = cp ? t2[col + 1] : 0.f;
  float e0 = cm ? t2[256 + col - 1] : 0.f, e1 = t2[256 + col], e2 = cp ? t2[256 + col + 1] : 0.f;
  u16* op = out + (size_t)c * NPLANE + (size_t)r0 * 256 + col;
#pragma unroll
  for (int rr = 0; rr < 16; ++rr) {
    const int rn = (rr + 2) * 256;
    const float c1 = t1[rn + col];
    const float c0 = cm ? t1[rn + col - 1] : 0.f;
    const float c2 = cp ? t1[rn + col + 1] : 0.f;
    const float g1 = wa[0] * a0 + wa[1] * a1 + wa[2] * a2
                   + wa[3] * b0 + wa[4] * b1 + wa[5] * b2
                   + wa[6] * c0 + wa[7] * c1 + wa[8] * c2;
    const float f1 = t2[rn + col];
    const float f0 = cm ? t2[rn + col - 1] : 0.f;
    const float f2 = cp ? t2[rn + col + 1] : 0.f;
    const float g2 = wb[0] * d0 + wb[1] * d1 + wb[2] * d2
                   + wb[3] * e0 + wb[4] * e1 + wb[5] * e2
                   + wb[6] * f0 + wb[7] * f1 + wb[8] * f2;
    const float gel = 0.5f * g1 * (1.f + erff(g1 * 0.70710678118654752f));
    op[rr * 256] = f2bf(gel * g2);
    a0 = b0; a1 = b1; a2 = b2; b0 = c0; b1 = c1; b2 = c2;
    d0 = e0; d1 = e1; d2 = e2; e0 = f0; e1 = f1; e2 = f2;
  }
}

// ---------------- MFMA Gram: G = [q;k]·[q;k]^T per head/chunk -> S quadrant + norms
__global__ __launch_bounds__(256) void k_reduce_s(
    const u16* __restrict__ qkv, float* __restrict__ S,
    float* __restrict__ qn2, float* __restrict__ kn2)
{
  const int h = blockIdx.y;
  const int n0 = blockIdx.x * 512;
  __shared__ uint4 st[64 * 33];
  const int tid = threadIdx.x;
  const int l = tid & 63, w = tid >> 6;

#pragma unroll
  for (int i = 0; i < 8; ++i) {
    const int idx = tid + i * 256;
    const int c = idx & 63, r = idx >> 6;
    const int plane = (r < 16) ? (h * 16 + r) : (96 + h * 16 + (r - 16));
    st[c * 33 + r] = *(const uint4*)(qkv + (size_t)plane * NPLANE + n0 + c * 8);
  }
  __syncthreads();

  f32x16 acc;
#pragma unroll
  for (int j = 0; j < 16; ++j) acc[j] = 0.f;
  const int row = l & 31;
  const int cg = (w << 4) + (l >> 5);
#pragma unroll
  for (int s = 0; s < 8; ++s) {
    U16x8 frag;
    frag.u4 = st[(cg + s * 2) * 33 + row];
    acc = __builtin_amdgcn_mfma_f32_32x32x16_bf16(frag.v, frag.v, acc, 0, 0, 0);
  }
  __syncthreads();

  float* fs = (float*)st;
#pragma unroll
  for (int j = 0; j < 16; ++j) {
    const int rj = (j & 3) + 8 * (j >> 2) + 4 * (l >> 5);
    fs[w * 1024 + rj * 32 + (l & 31)] = acc[j];
  }
  __syncthreads();
#pragma unroll
  for (int e4 = 0; e4 < 4; ++e4) {
    const int e = tid * 4 + e4;
    const float v = fs[e] + fs[1024 + e] + fs[2048 + e] + fs[3072 + e];
    const int r = e >> 5, cc = e & 31;
    if (r < 16 && cc >= 16) atomicAdd(S + h * 256 + r * 16 + (cc - 16), v);
    if (r == cc) {
      if (r < 16) atomicAdd(qn2 + h * 16 + r, v);
      else        atomicAdd(kn2 + h * 16 + (r - 16), v);
    }
  }
}

// ---------------- softmax + fold proj -> Mtb bf16 [e][dg] (96x96)
__global__ __launch_bounds__(256) void k_softmax_m(
    const float* __restrict__ S, const float* __restrict__ qn2, const float* __restrict__ kn2,
    const float* __restrict__ temp, const float* __restrict__ proj, u16* __restrict__ Mtb)
{
  __shared__ float attn[6 * 256];
  const int tid = threadIdx.x;
  if (tid < 96) {
    const int h = tid >> 4, i = tid & 15;
    const float qn = fmaxf(sqrtf(qn2[tid]), 1e-12f);
    const float tp = temp[h];
    float row[16];
    float mx = -3.4e38f;
#pragma unroll
    for (int d = 0; d < 16; ++d) {
      const float kn = fmaxf(sqrtf(kn2[h * 16 + d]), 1e-12f);
      row[d] = S[h * 256 + i * 16 + d] / (qn * kn) * tp;
      mx = fmaxf(mx, row[d]);
    }
    float sum = 0.f;
#pragma unroll
    for (int d = 0; d < 16; ++d) { row[d] = expf(row[d] - mx); sum += row[d]; }
    const float inv = 1.f / sum;
#pragma unroll
    for (int d = 0; d < 16; ++d) attn[h * 256 + i * 16 + d] = row[d] * inv;
  }
  __syncthreads();
  for (int u = tid; u < 9216; u += 256) {
    const int e = u / 96, dg = u - e * 96;
    const int h = dg >> 4, d = dg & 15;
    float s = 0.f;
#pragma unroll
    for (int i = 0; i < 16; ++i)
      s += proj[e * 96 + h * 16 + i] * attn[h * 256 + i * 16 + d];
    Mtb[u] = f2bf(s);
  }
}

extern "C" void kernel_launch(void* const* d_in, const int* in_sizes, int n_in,
                              void* d_out, int out_size, void* d_ws, size_t ws_size,
                              hipStream_t stream)
{
  (void)in_sizes; (void)n_in; (void)out_size;
  if (ws_size < (size_t)130400000) return;

  const void* Fw  = d_in[0];
  const void* F0c = d_in[1];
  const void* Kdi = d_in[2];

  char* ws = (char*)d_ws;
  u16* xcur = (u16*)ws;
  u16* bufA = (u16*)(ws + 25165824);
  u16* bufB = (u16*)(ws + 92012544);
  u16* wb   = (u16*)(ws + 129761280);
  u16* Wq1 = wb;           u16* Wi1 = wb + 27648;   u16* Wo1 = wb + 82944;
  u16* Wq2 = wb + 107520;  u16* Wi2 = wb + 135168;  u16* Wo2 = wb + 190464;
  u16* Mtb = wb + 215040;  // 96x96
  float* fz = (float*)(ws + 130209792);
  float* dwA1 = fz;          float* dwF1 = fz + 2592;
  float* dwA2 = fz + 7182;   float* dwF2 = fz + 9774;
  float* prj1 = fz + 14364;  float* prj2 = fz + 23580;
  float* tmp1 = fz + 32796;  float* tmp2 = fz + 32802;
  float* lnp  = fz + 32808;  // 8 x 96
  float* Sb   = fz + 33576;  float* Qn = fz + 35112;  float* Kn = fz + 35208;
  u32*  flag  = (u32*)(fz + 35304);

  k_detect<<<1, 64, 0, stream>>>((const u16*)d_in[3], flag);

  k_wprep<<<dim3(108), 256, 0, stream>>>(d_in[5],  Wq1, 288, 96, 96,  27648, flag);
  k_wprep<<<dim3(216), 256, 0, stream>>>(d_in[11], Wi1, 510, 96, 96,  55296, flag);
  k_wprep<<<dim3(96),  256, 0, stream>>>(d_in[13], Wo1, 96,  255, 256, 24576, flag);
  k_wprep<<<dim3(108), 256, 0, stream>>>(d_in[16], Wq2, 288, 96, 96,  27648, flag);
  k_wprep<<<dim3(216), 256, 0, stream>>>(d_in[22], Wi2, 510, 96, 96,  55296, flag);
  k_wprep<<<dim3(96),  256, 0, stream>>>(d_in[24], Wo2, 96,  255, 256, 24576, flag);

  k_cvt_f32<<<dim3(11), 256, 0, stream>>>(d_in[6],  dwA1, 2592, flag);
  k_cvt_f32<<<dim3(18), 256, 0, stream>>>(d_in[12], dwF1, 4590, flag);
  k_cvt_f32<<<dim3(11), 256, 0, stream>>>(d_in[17], dwA2, 2592, flag);
  k_cvt_f32<<<dim3(18), 256, 0, stream>>>(d_in[23], dwF2, 4590, flag);
  k_cvt_f32<<<dim3(36), 256, 0, stream>>>(d_in[7],  prj1, 9216, flag);
  k_cvt_f32<<<dim3(36), 256, 0, stream>>>(d_in[18], prj2, 9216, flag);
  k_cvt_f32<<<dim3(1), 256, 0, stream>>>(d_in[8],  tmp1, 6, flag);
  k_cvt_f32<<<dim3(1), 256, 0, stream>>>(d_in[19], tmp2, 6, flag);
  k_cvt_f32<<<dim3(1), 256, 0, stream>>>(d_in[3],  lnp + 0,   96, flag);
  k_cvt_f32<<<dim3(1), 256, 0, stream>>>(d_in[4],  lnp + 96,  96, flag);
  k_cvt_f32<<<dim3(1), 256, 0, stream>>>(d_in[9],  lnp + 192, 96, flag);
  k_cvt_f32<<<dim3(1), 256, 0, stream>>>(d_in[10], lnp + 288, 96, flag);
  k_cvt_f32<<<dim3(1), 256, 0, stream>>>(d_in[14], lnp + 384, 96, flag);
  k_cvt_f32<<<dim3(1), 256, 0, stream>>>(d_in[15], lnp + 480, 96, flag);
  k_cvt_f32<<<dim3(1), 256, 0, stream>>>(d_in[20], lnp + 576, 96, flag);
  k_cvt_f32<<<dim3(1), 256, 0, stream>>>(d_in[21], lnp + 672, 96, flag);

  // attn: out = res + proj(attn(dw(conv(LN(x)+f))))
  auto attn_stage = [&](const void* x, const u32* xfl, const void* f, const u32* ffl,
                        const float* lw, const float* lb, const u16* Wq,
                        const float* dwf, const float* tmpf, const float* prjf,
                        const void* res, const u32* rfl,
                        void* outx, const u32* ofl) {
    for (int b = 0; b < 2; ++b) {
      const size_t eb = (size_t)b * BELEMS;
      hipMemsetAsync(Sb, 0, 1728 * sizeof(float), stream);
      k_lnp<<<dim3(1024), 256, 0, stream>>>(x, xfl, f, ffl, eb, lw, lb, bufB);
      k_gemm_bt<<<dim3(3, 512), 256, 0, stream>>>(bufB, Wq, 288, bufA);
      k_dw<<<dim3(16, 288), 256, 0, stream>>>(bufA, dwf, bufB);
      k_reduce_s<<<dim3(128, 6), 256, 0, stream>>>(bufB, Sb, Qn, Kn);
      k_softmax_m<<<dim3(1), 256, 0, stream>>>(Sb, Qn, Kn, tmpf, prjf, Mtb);
      k_gemm<<<dim3(1, 512), 256, 0, stream>>>(bufB + (size_t)192 * NPLANE, nullptr, 0,
                                               nullptr, nullptr, nullptr, nullptr,
                                               Mtb, 96, 96, 96,
                                               res, rfl, outx, ofl, eb);
    }
  };
  auto ffn_stage = [&](const void* x, const u32* xfl,
                       const float* lw, const float* lb, const u16* Wi,
                       const float* dwf, const u16* Wo,
                       void* outx, const u32* ofl) {
    for (int b = 0; b < 2; ++b) {
      const size_t eb = (size_t)b * BELEMS;
      k_lnp<<<dim3(1024), 256, 0, stream>>>(x, xfl, nullptr, nullptr, eb, lw, lb, bufB);
      k_gemm_bt<<<dim3(6, 512), 256, 0, stream>>>(bufB, Wi, 510, bufA);
      k_dw_gelu<<<dim3(16, 255), 256, 0, stream>>>(bufA, dwf, bufB);
      k_gemm<<<dim3(1, 512), 256, 0, stream>>>(bufB, nullptr, 0,
                                               nullptr, nullptr, nullptr, nullptr,
                                               Wo, 255, 256, 96,
                                               x, xfl, outx, ofl, eb);
    }
  };

  // stage 1: x1 = Fw + attn(LN1(Fw) + F0c)
  attn_stage(Fw, flag, F0c, flag, lnp + 0, lnp + 96, Wq1, dwA1, tmp1, prj1,
             Fw, flag, xcur, nullptr);
  // stage 2: x2 = x1 + ffn(LN2(x1))
  ffn_stage(xcur, nullptr, lnp + 192, lnp + 288, Wi1, dwF1, Wo1, xcur, nullptr);
  // stage 3: x3 = x2 + attn(LN3(x2) + Kd)
  attn_stage(xcur, nullptr, Kdi, flag, lnp + 384, lnp + 480, Wq2, dwA2, tmp2, prj2,
             xcur, nullptr, xcur, nullptr);
  // stage 4: out = x3 + ffn(LN4(x3))
  ffn_stage(xcur, nullptr, lnp + 576, lnp + 672, Wi2, dwF2, Wo2, d_out, flag);
}